// Round 3
// baseline (2363.305 us; speedup 1.0000x reference)
//
#include <hip/hip_runtime.h>
#include <hip/hip_bf16.h>

#define NUM_NODES 100000
#define NUM_EDGES 100000
#define NNZ       1600000
#define D         64

#define BKT       128                       // targets per bucket
#define NBKT_E    ((NUM_EDGES + BKT - 1) / BKT)   // 782
#define NBKT_V    ((NUM_NODES + BKT - 1) / BKT)   // 782
#define NBKT_TOT  (NBKT_E + NBKT_V)               // 1564
#define ACC_STRIDE 68                       // 64 + 4 pad (bank decorrelation)

// ---------------------------------------------------------------------------
// Kernel 1: Xp = X @ W^T + b
// ---------------------------------------------------------------------------
#define GEMM_ROWS 32
__global__ __launch_bounds__(256) void gemm_xw(
    const float* __restrict__ X, const float* __restrict__ W,
    const float* __restrict__ b, float* __restrict__ Xp) {
  __shared__ float Wl[D][D + 1];
  __shared__ float Xl[GEMM_ROWS][D];
  const int t = threadIdx.x;

  for (int j = t; j < D * D; j += 256) Wl[j >> 6][j & 63] = W[j];
  const int row0 = blockIdx.x * GEMM_ROWS;
  const float4* X4 = (const float4*)(X + (size_t)row0 * D);
  float4* Xl4 = (float4*)&Xl[0][0];
  for (int j = t; j < GEMM_ROWS * (D / 4); j += 256) Xl4[j] = X4[j];
  __syncthreads();

  const int c = t & 63;
  const int rq = t >> 6;
  float acc[8];
#pragma unroll
  for (int i = 0; i < 8; ++i) acc[i] = 0.f;
#pragma unroll
  for (int k = 0; k < D; ++k) {
    const float w = Wl[c][k];
#pragma unroll
    for (int i = 0; i < 8; ++i) acc[i] = fmaf(Xl[rq + i * 4][k], w, acc[i]);
  }
  const float bias = b[c];
#pragma unroll
  for (int i = 0; i < 8; ++i) {
    const int r = row0 + rq + i * 4;
    Xp[(size_t)r * D + c] = acc[i] + bias;
  }
}

// ---------------------------------------------------------------------------
// Kernel 2: bucket histogram (1564 counters) + node-degree histogram D_v
// ---------------------------------------------------------------------------
__global__ __launch_bounds__(256) void hist2_k(
    const int* __restrict__ V, const int* __restrict__ E,
    int* __restrict__ cnt, int* __restrict__ D_v) {
  const int i = blockIdx.x * blockDim.x + threadIdx.x;
  if (i < NNZ) {
    const int v = V[i], e = E[i];
    atomicAdd(&cnt[e >> 7], 1);
    atomicAdd(&cnt[NBKT_E + (v >> 7)], 1);
    atomicAdd(&D_v[v], 1);
  }
}

// ---------------------------------------------------------------------------
// Kernel 3: exclusive scan of cnt[1564] -> off[1565], cursor = off
// Single block, 256 threads x 7 elements.
// ---------------------------------------------------------------------------
__global__ __launch_bounds__(256) void scan_k(
    const int* __restrict__ cnt, int* __restrict__ off, int* __restrict__ cursor) {
  __shared__ int part[256];
  const int t = threadIdx.x;
  int loc[7];
  int s = 0;
#pragma unroll
  for (int j = 0; j < 7; ++j) {
    const int idx = t * 7 + j;
    const int v = (idx < NBKT_TOT) ? cnt[idx] : 0;
    loc[j] = s;
    s += v;
  }
  part[t] = s;
  __syncthreads();
  for (int st = 1; st < 256; st <<= 1) {
    const int v = part[t];
    const int add = (t >= st) ? part[t - st] : 0;
    __syncthreads();
    part[t] = v + add;
    __syncthreads();
  }
  const int base = (t == 0) ? 0 : part[t - 1];
#pragma unroll
  for (int j = 0; j < 7; ++j) {
    const int idx = t * 7 + j;
    if (idx < NBKT_TOT) {
      const int o = base + loc[j];
      off[idx] = o;
      cursor[idx] = o;
    }
  }
  if (t == 255) off[NBKT_TOT] = part[255];   // = 2*NNZ
}

// ---------------------------------------------------------------------------
// Kernel 4: bin — scatter packed pair words into bucket-contiguous segments.
// Edge side word: (v << 7) | (e & 127); node side word: (e << 7) | (v & 127).
// Only ~1564 write frontiers are hot -> dense line fill, no amplification.
// ---------------------------------------------------------------------------
__global__ __launch_bounds__(256) void bin_k(
    const int* __restrict__ V, const int* __restrict__ E,
    int* __restrict__ cursor, unsigned* __restrict__ pair) {
  const int i = blockIdx.x * blockDim.x + threadIdx.x;
  if (i < NNZ) {
    const int v = V[i], e = E[i];
    const unsigned we = ((unsigned)v << 7) | (unsigned)(e & 127);
    const int p = atomicAdd(&cursor[e >> 7], 1);
    pair[p] = we;
    const unsigned wv = ((unsigned)e << 7) | (unsigned)(v & 127);
    const int p2 = atomicAdd(&cursor[NBKT_E + (v >> 7)], 1);
    pair[p2] = wv;
  }
}

// ---------------------------------------------------------------------------
// Kernel 5: per-edge-bucket accumulate. 128 edge rows live in LDS; gather
// Xp rows (float4 / lane-quad), LDS fp32 atomics; fused De/cnt normalization.
// ---------------------------------------------------------------------------
__global__ __launch_bounds__(256) void accum_edge_k(
    const int* __restrict__ off, const unsigned* __restrict__ pair,
    const int* __restrict__ D_v, const float* __restrict__ Xp,
    float* __restrict__ Y) {
  __shared__ float acc[BKT * ACC_STRIDE];
  __shared__ int scnt[BKT];
  __shared__ int sdsum[BKT];
  __shared__ float sscale[BKT];
  const int b = blockIdx.x;
  const int t = threadIdx.x;
  const int q = t & 15;
  const int quad = t >> 4;                 // 16 quads

  for (int j = t; j < BKT * ACC_STRIDE; j += 256) acc[j] = 0.f;
  if (t < BKT) { scnt[t] = 0; sdsum[t] = 0; }
  __syncthreads();

  const int beg = off[b], end = off[b + 1];
  const float4* Xp4 = (const float4*)Xp;

  int p = beg + quad;
  for (; p + 16 < end; p += 32) {
#pragma unroll
    for (int u = 0; u < 2; ++u) {
      const unsigned w = pair[p + u * 16];
      const int row = (int)(w & 127u);
      const int v = (int)(w >> 7);
      const float4 x = Xp4[v * 16 + q];
      float* a = &acc[row * ACC_STRIDE + q * 4];
      atomicAdd(a + 0, x.x);
      atomicAdd(a + 1, x.y);
      atomicAdd(a + 2, x.z);
      atomicAdd(a + 3, x.w);
      if (q == 0) {
        atomicAdd(&scnt[row], 1);
        atomicAdd(&sdsum[row], D_v[v]);
      }
    }
  }
  if (p < end) {
    const unsigned w = pair[p];
    const int row = (int)(w & 127u);
    const int v = (int)(w >> 7);
    const float4 x = Xp4[v * 16 + q];
    float* a = &acc[row * ACC_STRIDE + q * 4];
    atomicAdd(a + 0, x.x);
    atomicAdd(a + 1, x.y);
    atomicAdd(a + 2, x.z);
    atomicAdd(a + 3, x.w);
    if (q == 0) {
      atomicAdd(&scnt[row], 1);
      atomicAdd(&sdsum[row], D_v[v]);
    }
  }
  __syncthreads();

  if (t < BKT) {
    const float cf = (float)scnt[t];
    const float De = (float)sdsum[t] / (cf + 1.f);
    const float inv = (De > 0.f) ? rsqrtf(fmaxf(De, 1e-30f)) : 1.f;
    sscale[t] = inv / fmaxf(cf, 1.f);
  }
  __syncthreads();

  float4* Y4 = (float4*)Y;
  for (int s = t; s < BKT * 16; s += 256) {
    const int row = s >> 4, q2 = s & 15;
    const int e = b * BKT + row;
    if (e < NUM_EDGES) {
      const float sc = sscale[row];
      const float* a = &acc[row * ACC_STRIDE + q2 * 4];
      Y4[e * 16 + q2] = make_float4(a[0] * sc, a[1] * sc, a[2] * sc, a[3] * sc);
    }
  }
}

// ---------------------------------------------------------------------------
// Kernel 6: per-node-bucket accumulate. Out[v] = rsqrt(D_v) * sum Y[e].
// ---------------------------------------------------------------------------
__global__ __launch_bounds__(256) void accum_node_k(
    const int* __restrict__ off, const unsigned* __restrict__ pair,
    const float* __restrict__ Y, float* __restrict__ Out) {
  __shared__ float acc[BKT * ACC_STRIDE];
  __shared__ int scnt[BKT];
  __shared__ float sscale[BKT];
  const int b = blockIdx.x;
  const int t = threadIdx.x;
  const int q = t & 15;
  const int quad = t >> 4;

  for (int j = t; j < BKT * ACC_STRIDE; j += 256) acc[j] = 0.f;
  if (t < BKT) scnt[t] = 0;
  __syncthreads();

  const int beg = off[NBKT_E + b], end = off[NBKT_E + b + 1];
  const float4* Y4 = (const float4*)Y;

  int p = beg + quad;
  for (; p + 16 < end; p += 32) {
#pragma unroll
    for (int u = 0; u < 2; ++u) {
      const unsigned w = pair[p + u * 16];
      const int row = (int)(w & 127u);
      const int e = (int)(w >> 7);
      const float4 y = Y4[e * 16 + q];
      float* a = &acc[row * ACC_STRIDE + q * 4];
      atomicAdd(a + 0, y.x);
      atomicAdd(a + 1, y.y);
      atomicAdd(a + 2, y.z);
      atomicAdd(a + 3, y.w);
      if (q == 0) atomicAdd(&scnt[row], 1);
    }
  }
  if (p < end) {
    const unsigned w = pair[p];
    const int row = (int)(w & 127u);
    const int e = (int)(w >> 7);
    const float4 y = Y4[e * 16 + q];
    float* a = &acc[row * ACC_STRIDE + q * 4];
    atomicAdd(a + 0, y.x);
    atomicAdd(a + 1, y.y);
    atomicAdd(a + 2, y.z);
    atomicAdd(a + 3, y.w);
    if (q == 0) atomicAdd(&scnt[row], 1);
  }
  __syncthreads();

  if (t < BKT) {
    const float d = (float)scnt[t];
    sscale[t] = (d > 0.f) ? rsqrtf(d) : 0.f;
  }
  __syncthreads();

  float4* Out4 = (float4*)Out;
  for (int s = t; s < BKT * 16; s += 256) {
    const int row = s >> 4, q2 = s & 15;
    const int v = b * BKT + row;
    if (v < NUM_NODES) {
      const float sc = sscale[row];
      const float* a = &acc[row * ACC_STRIDE + q2 * 4];
      Out4[v * 16 + q2] = make_float4(a[0] * sc, a[1] * sc, a[2] * sc, a[3] * sc);
    }
  }
}

extern "C" void kernel_launch(void* const* d_in, const int* in_sizes, int n_in,
                              void* d_out, int out_size, void* d_ws, size_t ws_size,
                              hipStream_t stream) {
  const float* X = (const float*)d_in[0];
  const int*   V = (const int*)d_in[1];
  const int*   E = (const int*)d_in[2];
  const float* W = (const float*)d_in[4];
  const float* b = (const float*)d_in[5];
  float* Out = (float*)d_out;

  // workspace layout (~64.5 MB)
  float*    Xp     = (float*)d_ws;                       // 25.6 MB
  float*    Y      = Xp + (size_t)NUM_NODES * D;         // 25.6 MB
  int*      D_v    = (int*)(Y + (size_t)NUM_EDGES * D);  // 400 KB
  int*      cnt    = D_v + NUM_NODES;                    // 1564
  int*      off    = cnt + NBKT_TOT;                     // 1565
  int*      cursor = off + NBKT_TOT + 1;                 // 1564
  unsigned* pair   = (unsigned*)(cursor + NBKT_TOT);     // 2*NNZ = 12.8 MB

  // zero D_v + cnt (contiguous)
  hipMemsetAsync(D_v, 0, (size_t)(NUM_NODES + NBKT_TOT) * sizeof(int), stream);

  gemm_xw<<<NUM_NODES / GEMM_ROWS, 256, 0, stream>>>(X, W, b, Xp);
  hist2_k<<<(NNZ + 255) / 256, 256, 0, stream>>>(V, E, cnt, D_v);
  scan_k<<<1, 256, 0, stream>>>(cnt, off, cursor);
  bin_k<<<(NNZ + 255) / 256, 256, 0, stream>>>(V, E, cursor, pair);
  accum_edge_k<<<NBKT_E, 256, 0, stream>>>(off, pair, D_v, Xp, Y);
  accum_node_k<<<NBKT_V, 256, 0, stream>>>(off, pair, Y, Out);
}

// Round 4
// 839.117 us; speedup vs baseline: 2.8164x; 2.8164x over previous
//
#include <hip/hip_runtime.h>
#include <hip/hip_bf16.h>

#define NUM_NODES 100000
#define NUM_EDGES 100000
#define NNZ       1600000
#define D         64

#define N2 (NUM_EDGES + NUM_NODES)          // 200000 concatenated targets
#define SCAN_B 256
#define NB ((N2 + SCAN_B - 1) / SCAN_B)     // 782

#define BKT     128                          // targets per bucket
#define NBKT_E  ((NUM_EDGES + BKT - 1) / BKT)   // 782
#define NBKT_V  ((NUM_NODES + BKT - 1) / BKT)   // 782
#define NBKT_TOT (NBKT_E + NBKT_V)              // 1564
#define SEG_CAP 3072                         // LDS staging capacity (mean 2048, +22 sigma)

// ---------------------------------------------------------------------------
// Kernel 1: Xp = X @ W^T + b
// ---------------------------------------------------------------------------
#define GEMM_ROWS 32
__global__ __launch_bounds__(256) void gemm_xw(
    const float* __restrict__ X, const float* __restrict__ W,
    const float* __restrict__ b, float* __restrict__ Xp) {
  __shared__ float Wl[D][D + 1];
  __shared__ float Xl[GEMM_ROWS][D];
  const int t = threadIdx.x;

  for (int j = t; j < D * D; j += 256) Wl[j >> 6][j & 63] = W[j];
  const int row0 = blockIdx.x * GEMM_ROWS;
  const float4* X4 = (const float4*)(X + (size_t)row0 * D);
  float4* Xl4 = (float4*)&Xl[0][0];
  for (int j = t; j < GEMM_ROWS * (D / 4); j += 256) Xl4[j] = X4[j];
  __syncthreads();

  const int c = t & 63;
  const int rq = t >> 6;
  float acc[8];
#pragma unroll
  for (int i = 0; i < 8; ++i) acc[i] = 0.f;
#pragma unroll
  for (int k = 0; k < D; ++k) {
    const float w = Wl[c][k];
#pragma unroll
    for (int i = 0; i < 8; ++i) acc[i] = fmaf(Xl[rq + i * 4][k], w, acc[i]);
  }
  const float bias = b[c];
#pragma unroll
  for (int i = 0; i < 8; ++i) {
    const int r = row0 + rq + i * 4;
    Xp[(size_t)r * D + c] = acc[i] + bias;
  }
}

// ---------------------------------------------------------------------------
// Kernel 2: histogram — cnt[e]++ (edge size), cnt[NUM_EDGES+v]++ (degree)
// ---------------------------------------------------------------------------
__global__ __launch_bounds__(256) void hist_k(
    const int* __restrict__ V, const int* __restrict__ E, int* __restrict__ cnt) {
  const int i = blockIdx.x * blockDim.x + threadIdx.x;
  if (i < NNZ) {
    atomicAdd(&cnt[E[i]], 1);
    atomicAdd(&cnt[NUM_EDGES + V[i]], 1);
  }
}

// ---------------------------------------------------------------------------
// Exclusive scan over cnt[N2] -> off[N2+1]  (3 kernels, round-2 proven)
// ---------------------------------------------------------------------------
__global__ __launch_bounds__(SCAN_B) void scan_reduce_k(
    const int* __restrict__ cnt, int* __restrict__ bsum) {
  __shared__ int s[SCAN_B];
  const int t = threadIdx.x, b = blockIdx.x, i = b * SCAN_B + t;
  s[t] = (i < N2) ? cnt[i] : 0;
  __syncthreads();
  for (int st = SCAN_B / 2; st > 0; st >>= 1) {
    if (t < st) s[t] += s[t + st];
    __syncthreads();
  }
  if (t == 0) bsum[b] = s[0];
}

__global__ __launch_bounds__(1024) void scan_mid_k(
    const int* __restrict__ bsum, int* __restrict__ boff) {
  __shared__ int s[1024];
  const int t = threadIdx.x;
  s[t] = (t < NB) ? bsum[t] : 0;
  __syncthreads();
  for (int st = 1; st < 1024; st <<= 1) {
    const int v = s[t];
    const int add = (t >= st) ? s[t - st] : 0;
    __syncthreads();
    s[t] = v + add;
    __syncthreads();
  }
  if (t < NB) boff[t] = (t == 0) ? 0 : s[t - 1];
}

__global__ __launch_bounds__(SCAN_B) void scan_final_k(
    const int* __restrict__ cnt, const int* __restrict__ boff,
    int* __restrict__ off) {
  __shared__ int s[SCAN_B];
  const int t = threadIdx.x, b = blockIdx.x, i = b * SCAN_B + t;
  const int x = (i < N2) ? cnt[i] : 0;
  s[t] = x;
  __syncthreads();
  for (int st = 1; st < SCAN_B; st <<= 1) {
    const int v = s[t];
    const int add = (t >= st) ? s[t - st] : 0;
    __syncthreads();
    s[t] = v + add;
    __syncthreads();
  }
  if (i < N2) off[i] = boff[b] + s[t] - x;   // exclusive
  if (i == N2 - 1) off[N2] = boff[b] + s[t];
}

// ---------------------------------------------------------------------------
// Kernel: init bucket cursors from CSR offsets (buckets = 128 targets)
// ---------------------------------------------------------------------------
__global__ __launch_bounds__(256) void init_cursor_k(
    const int* __restrict__ off, int* __restrict__ curb) {
  const int b = blockIdx.x * blockDim.x + threadIdx.x;
  if (b < NBKT_E) {
    curb[b] = off[b * BKT];
  } else if (b < NBKT_TOT) {
    curb[b] = off[NUM_EDGES + (b - NBKT_E) * BKT];
  }
}

// ---------------------------------------------------------------------------
// Kernel: bin — scatter packed words into bucket-contiguous segments.
// Edge side: (v << 7) | (e & 127); node side: (e << 7) | (v & 127).
// Only 1564 hot write frontiers -> dense line fill (verified round 3).
// ---------------------------------------------------------------------------
__global__ __launch_bounds__(256) void bin_k(
    const int* __restrict__ V, const int* __restrict__ E,
    int* __restrict__ curb, unsigned* __restrict__ pair) {
  const int i = blockIdx.x * blockDim.x + threadIdx.x;
  if (i < NNZ) {
    const int v = V[i], e = E[i];
    const int p = atomicAdd(&curb[e >> 7], 1);
    pair[p] = ((unsigned)v << 7) | (unsigned)(e & 127);
    const int p2 = atomicAdd(&curb[NBKT_E + (v >> 7)], 1);
    pair[p2] = ((unsigned)e << 7) | (unsigned)(v & 127);
  }
}

// ---------------------------------------------------------------------------
// Kernel: per-bucket local CSR placement, IN PLACE over `pair`.
// Stage the segment into LDS, then scatter payloads to exact CSR positions
// (bucket CSR range == bucket segment range). Writes land in the block's own
// contiguous ~8 KB region -> dense.
// ---------------------------------------------------------------------------
__global__ __launch_bounds__(256) void fill_local_k(
    const int* __restrict__ off, unsigned* __restrict__ pair) {
  __shared__ unsigned seg[SEG_CAP];
  __shared__ int lcur[BKT];
  const int b = blockIdx.x, t = threadIdx.x;
  int ct0, nrows;
  if (b < NBKT_E) {
    const int e0 = b * BKT;
    ct0 = e0;
    nrows = (NUM_EDGES - e0 < BKT) ? (NUM_EDGES - e0) : BKT;
  } else {
    const int v0 = (b - NBKT_E) * BKT;
    ct0 = NUM_EDGES + v0;
    nrows = (NUM_NODES - v0 < BKT) ? (NUM_NODES - v0) : BKT;
  }
  const int beg = off[ct0], end = off[ct0 + nrows];
  const int n = end - beg;

  const int ncap = (n < SEG_CAP) ? n : SEG_CAP;
  for (int j = t; j < ncap; j += 256) seg[j] = pair[beg + j];
  // overflow insurance (statistically never taken; keeps correctness airtight)
  unsigned ex[4];
  int nex = 0;
  for (int j = SEG_CAP + t; j < n; j += 256)
    if (nex < 4) ex[nex++] = pair[beg + j];
  if (t < BKT) lcur[t] = (t < nrows) ? off[ct0 + t] : 0;
  __syncthreads();

  int* idx = (int*)pair;
  for (int j = t; j < ncap; j += 256) {
    const unsigned w = seg[j];
    const int pos = atomicAdd(&lcur[w & 127u], 1);
    idx[pos] = (int)(w >> 7);
  }
  for (int u = 0; u < nex; ++u) {
    const unsigned w = ex[u];
    const int pos = atomicAdd(&lcur[w & 127u], 1);
    idx[pos] = (int)(w >> 7);
  }
}

// ---------------------------------------------------------------------------
// Kernel: per-edge gather (16 lanes/edge, float4/lane, register accumulate).
// Fuses De_sum, De_inv, 1/cnt.  Unroll-2 for more outstanding loads.
// ---------------------------------------------------------------------------
__global__ __launch_bounds__(256) void edge_gather_k(
    const int* __restrict__ off, const int* __restrict__ idx,
    const int* __restrict__ cnt, const float* __restrict__ Xp,
    float* __restrict__ Y) {
  const int g = blockIdx.x * blockDim.x + threadIdx.x;
  const int e = g >> 4, q = g & 15;
  if (e >= NUM_EDGES) return;
  const int beg = off[e], end = off[e + 1];
  const float4* Xp4 = (const float4*)Xp;
  float4 acc = make_float4(0.f, 0.f, 0.f, 0.f);
  float dsum = 0.f;
  int m = beg;
  for (; m + 1 < end; m += 2) {
    const int v0 = idx[m], v1 = idx[m + 1];
    const float4 x0 = Xp4[v0 * 16 + q];
    const float4 x1 = Xp4[v1 * 16 + q];
    const float d0 = (float)cnt[NUM_EDGES + v0];
    const float d1 = (float)cnt[NUM_EDGES + v1];
    acc.x += x0.x + x1.x; acc.y += x0.y + x1.y;
    acc.z += x0.z + x1.z; acc.w += x0.w + x1.w;
    dsum += d0 + d1;
  }
  if (m < end) {
    const int v = idx[m];
    const float4 x = Xp4[v * 16 + q];
    acc.x += x.x; acc.y += x.y; acc.z += x.z; acc.w += x.w;
    dsum += (float)cnt[NUM_EDGES + v];
  }
  const float ce = (float)(end - beg);
  const float De = dsum / (ce + 1.f);
  const float inv = (De > 0.f) ? rsqrtf(fmaxf(De, 1e-30f)) : 1.f;
  const float s = inv / fmaxf(ce, 1.f);
  ((float4*)Y)[e * 16 + q] = make_float4(acc.x * s, acc.y * s, acc.z * s, acc.w * s);
}

// ---------------------------------------------------------------------------
// Kernel: per-node gather.  Out[v,:] = Dv_inv * sum_e Y[e,:]
// ---------------------------------------------------------------------------
__global__ __launch_bounds__(256) void node_gather_k(
    const int* __restrict__ off, const int* __restrict__ idx,
    const int* __restrict__ cnt, const float* __restrict__ Y,
    float* __restrict__ Out) {
  const int g = blockIdx.x * blockDim.x + threadIdx.x;
  const int v = g >> 4, q = g & 15;
  if (v >= NUM_NODES) return;
  const int beg = off[NUM_EDGES + v], end = off[NUM_EDGES + v + 1];
  const float4* Y4 = (const float4*)Y;
  float4 acc = make_float4(0.f, 0.f, 0.f, 0.f);
  int m = beg;
  for (; m + 1 < end; m += 2) {
    const int e0 = idx[m], e1 = idx[m + 1];
    const float4 y0 = Y4[e0 * 16 + q];
    const float4 y1 = Y4[e1 * 16 + q];
    acc.x += y0.x + y1.x; acc.y += y0.y + y1.y;
    acc.z += y0.z + y1.z; acc.w += y0.w + y1.w;
  }
  if (m < end) {
    const float4 y = Y4[idx[m] * 16 + q];
    acc.x += y.x; acc.y += y.y; acc.z += y.z; acc.w += y.w;
  }
  const float d = (float)cnt[NUM_EDGES + v];
  const float s = (d > 0.f) ? rsqrtf(d) : 0.f;
  ((float4*)Out)[v * 16 + q] = make_float4(acc.x * s, acc.y * s, acc.z * s, acc.w * s);
}

extern "C" void kernel_launch(void* const* d_in, const int* in_sizes, int n_in,
                              void* d_out, int out_size, void* d_ws, size_t ws_size,
                              hipStream_t stream) {
  const float* X = (const float*)d_in[0];
  const int*   V = (const int*)d_in[1];
  const int*   E = (const int*)d_in[2];
  const float* W = (const float*)d_in[4];
  const float* b = (const float*)d_in[5];
  float* Out = (float*)d_out;

  // workspace layout (~64.9 MB)
  float*    Xp   = (float*)d_ws;                       // 25.6 MB
  float*    Y    = Xp + (size_t)NUM_NODES * D;         // 25.6 MB
  int*      cnt  = (int*)(Y + (size_t)NUM_EDGES * D);  // 800 KB
  int*      off  = cnt + N2;                           // 800 KB (+1)
  int*      bsum = off + N2 + 1;                       // 1024
  int*      boff = bsum + 1024;                        // 1024
  int*      curb = boff + 1024;                        // 1564
  unsigned* pair = (unsigned*)(curb + NBKT_TOT);       // 2*NNZ = 12.8 MB (becomes idx)
  int*      idx  = (int*)pair;                         // in-place CSR result

  hipMemsetAsync(cnt, 0, (size_t)N2 * sizeof(int), stream);

  gemm_xw<<<NUM_NODES / GEMM_ROWS, 256, 0, stream>>>(X, W, b, Xp);
  hist_k<<<(NNZ + 255) / 256, 256, 0, stream>>>(V, E, cnt);
  scan_reduce_k<<<NB, SCAN_B, 0, stream>>>(cnt, bsum);
  scan_mid_k<<<1, 1024, 0, stream>>>(bsum, boff);
  scan_final_k<<<NB, SCAN_B, 0, stream>>>(cnt, boff, off);
  init_cursor_k<<<(NBKT_TOT + 255) / 256, 256, 0, stream>>>(off, curb);
  bin_k<<<(NNZ + 255) / 256, 256, 0, stream>>>(V, E, curb, pair);
  fill_local_k<<<NBKT_TOT, 256, 0, stream>>>(off, pair);
  edge_gather_k<<<NUM_EDGES * 16 / 256, 256, 0, stream>>>(off, idx, cnt, Xp, Y);
  node_gather_k<<<NUM_NODES * 16 / 256, 256, 0, stream>>>(off, idx, cnt, Y, Out);
}

// Round 5
// 420.414 us; speedup vs baseline: 5.6214x; 1.9959x over previous
//
#include <hip/hip_runtime.h>
#include <hip/hip_bf16.h>

#define NUM_NODES 100000
#define NUM_EDGES 100000
#define NNZ       1600000
#define D         64

#define N2 (NUM_EDGES + NUM_NODES)          // 200000 concatenated targets
#define SCAN_B 256
#define NB ((N2 + SCAN_B - 1) / SCAN_B)     // 782

#define BKT     128                          // targets per bucket
#define NBKT_E  ((NUM_EDGES + BKT - 1) / BKT)   // 782
#define NBKT_V  ((NUM_NODES + BKT - 1) / BKT)   // 782
#define NBKT_TOT (NBKT_E + NBKT_V)              // 1564
#define SEG_CAP 3072                         // LDS staging capacity (mean 2048, +22 sigma)

#define TILE 8192                            // entries per bin tile
#define NT_SIDE ((NNZ + TILE - 1) / TILE)    // 196 tiles per side

// ---------------------------------------------------------------------------
// Kernel 1: Xp = X @ W^T + b
// ---------------------------------------------------------------------------
#define GEMM_ROWS 32
__global__ __launch_bounds__(256) void gemm_xw(
    const float* __restrict__ X, const float* __restrict__ W,
    const float* __restrict__ b, float* __restrict__ Xp) {
  __shared__ float Wl[D][D + 1];
  __shared__ float Xl[GEMM_ROWS][D];
  const int t = threadIdx.x;

  for (int j = t; j < D * D; j += 256) Wl[j >> 6][j & 63] = W[j];
  const int row0 = blockIdx.x * GEMM_ROWS;
  const float4* X4 = (const float4*)(X + (size_t)row0 * D);
  float4* Xl4 = (float4*)&Xl[0][0];
  for (int j = t; j < GEMM_ROWS * (D / 4); j += 256) Xl4[j] = X4[j];
  __syncthreads();

  const int c = t & 63;
  const int rq = t >> 6;
  float acc[8];
#pragma unroll
  for (int i = 0; i < 8; ++i) acc[i] = 0.f;
#pragma unroll
  for (int k = 0; k < D; ++k) {
    const float w = Wl[c][k];
#pragma unroll
    for (int i = 0; i < 8; ++i) acc[i] = fmaf(Xl[rq + i * 4][k], w, acc[i]);
  }
  const float bias = b[c];
#pragma unroll
  for (int i = 0; i < 8; ++i) {
    const int r = row0 + rq + i * 4;
    Xp[(size_t)r * D + c] = acc[i] + bias;
  }
}

// ---------------------------------------------------------------------------
// Kernel 2: histogram — cnt[e]++ (edge size), cnt[NUM_EDGES+v]++ (degree)
// ---------------------------------------------------------------------------
__global__ __launch_bounds__(256) void hist_k(
    const int* __restrict__ V, const int* __restrict__ E, int* __restrict__ cnt) {
  const int i = blockIdx.x * blockDim.x + threadIdx.x;
  if (i < NNZ) {
    atomicAdd(&cnt[E[i]], 1);
    atomicAdd(&cnt[NUM_EDGES + V[i]], 1);
  }
}

// ---------------------------------------------------------------------------
// Exclusive scan over cnt[N2] -> off[N2+1]
// ---------------------------------------------------------------------------
__global__ __launch_bounds__(SCAN_B) void scan_reduce_k(
    const int* __restrict__ cnt, int* __restrict__ bsum) {
  __shared__ int s[SCAN_B];
  const int t = threadIdx.x, b = blockIdx.x, i = b * SCAN_B + t;
  s[t] = (i < N2) ? cnt[i] : 0;
  __syncthreads();
  for (int st = SCAN_B / 2; st > 0; st >>= 1) {
    if (t < st) s[t] += s[t + st];
    __syncthreads();
  }
  if (t == 0) bsum[b] = s[0];
}

__global__ __launch_bounds__(1024) void scan_mid_k(
    const int* __restrict__ bsum, int* __restrict__ boff) {
  __shared__ int s[1024];
  const int t = threadIdx.x;
  s[t] = (t < NB) ? bsum[t] : 0;
  __syncthreads();
  for (int st = 1; st < 1024; st <<= 1) {
    const int v = s[t];
    const int add = (t >= st) ? s[t - st] : 0;
    __syncthreads();
    s[t] = v + add;
    __syncthreads();
  }
  if (t < NB) boff[t] = (t == 0) ? 0 : s[t - 1];
}

__global__ __launch_bounds__(SCAN_B) void scan_final_k(
    const int* __restrict__ cnt, const int* __restrict__ boff,
    int* __restrict__ off) {
  __shared__ int s[SCAN_B];
  const int t = threadIdx.x, b = blockIdx.x, i = b * SCAN_B + t;
  const int x = (i < N2) ? cnt[i] : 0;
  s[t] = x;
  __syncthreads();
  for (int st = 1; st < SCAN_B; st <<= 1) {
    const int v = s[t];
    const int add = (t >= st) ? s[t - st] : 0;
    __syncthreads();
    s[t] = v + add;
    __syncthreads();
  }
  if (i < N2) off[i] = boff[b] + s[t] - x;   // exclusive
  if (i == N2 - 1) off[N2] = boff[b] + s[t];
}

// ---------------------------------------------------------------------------
// Kernel: init bucket cursors from CSR offsets
// ---------------------------------------------------------------------------
__global__ __launch_bounds__(256) void init_cursor_k(
    const int* __restrict__ off, int* __restrict__ curb) {
  const int b = blockIdx.x * blockDim.x + threadIdx.x;
  if (b < NBKT_E) {
    curb[b] = off[b * BKT];
  } else if (b < NBKT_TOT) {
    curb[b] = off[NUM_EDGES + (b - NBKT_E) * BKT];
  }
}

// ---------------------------------------------------------------------------
// Kernel: tile-local counting sort + bulk-reserved contiguous write-out.
// One block = one 8192-entry tile of one side (side 0: edge-bucketed,
// side 1: node-bucketed). Per-bucket runs are written contiguously, and the
// global cursor gets ONE atomic per (tile, bucket) — kills both the
// same-address atomic serialization and the partial-line write amplification
// seen in round 4's bin_k (140 MB -> ~26 MB predicted).
// ---------------------------------------------------------------------------
__global__ __launch_bounds__(256) void bin_tile_k(
    const int* __restrict__ V, const int* __restrict__ E,
    int* __restrict__ curb, unsigned* __restrict__ pair) {
  __shared__ unsigned stage[TILE];            // 32 KB
  __shared__ unsigned short bkt16[TILE];      // 16 KB
  __shared__ int hist[NBKT_E];                // counts -> local offsets (in place)
  __shared__ int gbase[NBKT_E];
  __shared__ int lcur[NBKT_E];
  __shared__ int part[256];

  const int t = threadIdx.x;
  const int side = (blockIdx.x >= NT_SIDE) ? 1 : 0;
  const int bt = blockIdx.x - side * NT_SIDE;
  const int j0 = bt * TILE;
  const int n = (NNZ - j0 < TILE) ? (NNZ - j0) : TILE;
  const int cbase = side ? NBKT_E : 0;

  for (int i = t; i < NBKT_E; i += 256) hist[i] = 0;
  __syncthreads();

  // phase 1: bucket histogram for this tile
  for (int k = 0; k < TILE / 256; ++k) {
    const int j = j0 + t + k * 256;
    if (j - j0 < n) {
      const int key = side ? V[j] : E[j];
      atomicAdd(&hist[key >> 7], 1);
    }
  }
  __syncthreads();

  // phase 2: block scan of 782 counts + one global reservation per bucket
  int loc[4], cnt4[4];
  int s = 0;
#pragma unroll
  for (int u = 0; u < 4; ++u) {
    const int i = t * 4 + u;
    const int v = (i < NBKT_E) ? hist[i] : 0;
    cnt4[u] = v;
    loc[u] = s;
    s += v;
  }
  part[t] = s;
  __syncthreads();
  for (int st = 1; st < 256; st <<= 1) {
    const int v = part[t];
    const int add = (t >= st) ? part[t - st] : 0;
    __syncthreads();
    part[t] = v + add;
    __syncthreads();
  }
  const int base = (t == 0) ? 0 : part[t - 1];
#pragma unroll
  for (int u = 0; u < 4; ++u) {
    const int i = t * 4 + u;
    if (i < NBKT_E) {
      const int o = base + loc[u];
      hist[i] = o;                 // local exclusive offset
      lcur[i] = o;
      gbase[i] = cnt4[u] ? atomicAdd(&curb[cbase + i], cnt4[u]) : 0;
    }
  }
  __syncthreads();

  // phase 3: local scatter (bucket-sort the tile in LDS)
  for (int k = 0; k < TILE / 256; ++k) {
    const int j = j0 + t + k * 256;
    if (j - j0 < n) {
      const int v = V[j], e = E[j];
      const int key = side ? v : e;
      const int src = side ? e : v;
      const int b = key >> 7;
      const unsigned w = ((unsigned)src << 7) | (unsigned)(key & 127);
      const int pos = atomicAdd(&lcur[b], 1);
      stage[pos] = w;
      bkt16[pos] = (unsigned short)b;
    }
  }
  __syncthreads();

  // phase 4: write out — each bucket's run lands contiguously in global
  for (int sI = t; sI < n; sI += 256) {
    const int b = bkt16[sI];
    pair[gbase[b] + (sI - hist[b])] = stage[sI];
  }
}

// ---------------------------------------------------------------------------
// Kernel: per-bucket local CSR placement, IN PLACE over `pair`.
// ---------------------------------------------------------------------------
__global__ __launch_bounds__(256) void fill_local_k(
    const int* __restrict__ off, unsigned* __restrict__ pair) {
  __shared__ unsigned seg[SEG_CAP];
  __shared__ int lcur[BKT];
  const int b = blockIdx.x, t = threadIdx.x;
  int ct0, nrows;
  if (b < NBKT_E) {
    const int e0 = b * BKT;
    ct0 = e0;
    nrows = (NUM_EDGES - e0 < BKT) ? (NUM_EDGES - e0) : BKT;
  } else {
    const int v0 = (b - NBKT_E) * BKT;
    ct0 = NUM_EDGES + v0;
    nrows = (NUM_NODES - v0 < BKT) ? (NUM_NODES - v0) : BKT;
  }
  const int beg = off[ct0], end = off[ct0 + nrows];
  const int n = end - beg;

  const int ncap = (n < SEG_CAP) ? n : SEG_CAP;
  for (int j = t; j < ncap; j += 256) seg[j] = pair[beg + j];
  unsigned ex[4];
  int nex = 0;
  for (int j = SEG_CAP + t; j < n; j += 256)
    if (nex < 4) ex[nex++] = pair[beg + j];
  if (t < BKT) lcur[t] = (t < nrows) ? off[ct0 + t] : 0;
  __syncthreads();

  int* idx = (int*)pair;
  for (int j = t; j < ncap; j += 256) {
    const unsigned w = seg[j];
    const int pos = atomicAdd(&lcur[w & 127u], 1);
    idx[pos] = (int)(w >> 7);
  }
  for (int u = 0; u < nex; ++u) {
    const unsigned w = ex[u];
    const int pos = atomicAdd(&lcur[w & 127u], 1);
    idx[pos] = (int)(w >> 7);
  }
}

// ---------------------------------------------------------------------------
// Kernel: per-edge gather (16 lanes/edge, float4/lane, register accumulate).
// ---------------------------------------------------------------------------
__global__ __launch_bounds__(256) void edge_gather_k(
    const int* __restrict__ off, const int* __restrict__ idx,
    const int* __restrict__ cnt, const float* __restrict__ Xp,
    float* __restrict__ Y) {
  const int g = blockIdx.x * blockDim.x + threadIdx.x;
  const int e = g >> 4, q = g & 15;
  if (e >= NUM_EDGES) return;
  const int beg = off[e], end = off[e + 1];
  const float4* Xp4 = (const float4*)Xp;
  float4 acc = make_float4(0.f, 0.f, 0.f, 0.f);
  float dsum = 0.f;
  int m = beg;
  for (; m + 1 < end; m += 2) {
    const int v0 = idx[m], v1 = idx[m + 1];
    const float4 x0 = Xp4[v0 * 16 + q];
    const float4 x1 = Xp4[v1 * 16 + q];
    const float d0 = (float)cnt[NUM_EDGES + v0];
    const float d1 = (float)cnt[NUM_EDGES + v1];
    acc.x += x0.x + x1.x; acc.y += x0.y + x1.y;
    acc.z += x0.z + x1.z; acc.w += x0.w + x1.w;
    dsum += d0 + d1;
  }
  if (m < end) {
    const int v = idx[m];
    const float4 x = Xp4[v * 16 + q];
    acc.x += x.x; acc.y += x.y; acc.z += x.z; acc.w += x.w;
    dsum += (float)cnt[NUM_EDGES + v];
  }
  const float ce = (float)(end - beg);
  const float De = dsum / (ce + 1.f);
  const float inv = (De > 0.f) ? rsqrtf(fmaxf(De, 1e-30f)) : 1.f;
  const float s = inv / fmaxf(ce, 1.f);
  ((float4*)Y)[e * 16 + q] = make_float4(acc.x * s, acc.y * s, acc.z * s, acc.w * s);
}

// ---------------------------------------------------------------------------
// Kernel: per-node gather.  Out[v,:] = Dv_inv * sum_e Y[e,:]
// ---------------------------------------------------------------------------
__global__ __launch_bounds__(256) void node_gather_k(
    const int* __restrict__ off, const int* __restrict__ idx,
    const int* __restrict__ cnt, const float* __restrict__ Y,
    float* __restrict__ Out) {
  const int g = blockIdx.x * blockDim.x + threadIdx.x;
  const int v = g >> 4, q = g & 15;
  if (v >= NUM_NODES) return;
  const int beg = off[NUM_EDGES + v], end = off[NUM_EDGES + v + 1];
  const float4* Y4 = (const float4*)Y;
  float4 acc = make_float4(0.f, 0.f, 0.f, 0.f);
  int m = beg;
  for (; m + 1 < end; m += 2) {
    const int e0 = idx[m], e1 = idx[m + 1];
    const float4 y0 = Y4[e0 * 16 + q];
    const float4 y1 = Y4[e1 * 16 + q];
    acc.x += y0.x + y1.x; acc.y += y0.y + y1.y;
    acc.z += y0.z + y1.z; acc.w += y0.w + y1.w;
  }
  if (m < end) {
    const float4 y = Y4[idx[m] * 16 + q];
    acc.x += y.x; acc.y += y.y; acc.z += y.z; acc.w += y.w;
  }
  const float d = (float)cnt[NUM_EDGES + v];
  const float s = (d > 0.f) ? rsqrtf(d) : 0.f;
  ((float4*)Out)[v * 16 + q] = make_float4(acc.x * s, acc.y * s, acc.z * s, acc.w * s);
}

extern "C" void kernel_launch(void* const* d_in, const int* in_sizes, int n_in,
                              void* d_out, int out_size, void* d_ws, size_t ws_size,
                              hipStream_t stream) {
  const float* X = (const float*)d_in[0];
  const int*   V = (const int*)d_in[1];
  const int*   E = (const int*)d_in[2];
  const float* W = (const float*)d_in[4];
  const float* b = (const float*)d_in[5];
  float* Out = (float*)d_out;

  // workspace layout (~64.9 MB)
  float*    Xp   = (float*)d_ws;                       // 25.6 MB
  float*    Y    = Xp + (size_t)NUM_NODES * D;         // 25.6 MB
  int*      cnt  = (int*)(Y + (size_t)NUM_EDGES * D);  // 800 KB
  int*      off  = cnt + N2;                           // 800 KB (+1)
  int*      bsum = off + N2 + 1;                       // 1024
  int*      boff = bsum + 1024;                        // 1024
  int*      curb = boff + 1024;                        // 1564
  unsigned* pair = (unsigned*)(curb + NBKT_TOT);       // 2*NNZ = 12.8 MB (becomes idx)
  int*      idx  = (int*)pair;                         // in-place CSR result

  hipMemsetAsync(cnt, 0, (size_t)N2 * sizeof(int), stream);

  gemm_xw<<<NUM_NODES / GEMM_ROWS, 256, 0, stream>>>(X, W, b, Xp);
  hist_k<<<(NNZ + 255) / 256, 256, 0, stream>>>(V, E, cnt);
  scan_reduce_k<<<NB, SCAN_B, 0, stream>>>(cnt, bsum);
  scan_mid_k<<<1, 1024, 0, stream>>>(bsum, boff);
  scan_final_k<<<NB, SCAN_B, 0, stream>>>(cnt, boff, off);
  init_cursor_k<<<(NBKT_TOT + 255) / 256, 256, 0, stream>>>(off, curb);
  bin_tile_k<<<2 * NT_SIDE, 256, 0, stream>>>(V, E, curb, pair);
  fill_local_k<<<NBKT_TOT, 256, 0, stream>>>(off, pair);
  edge_gather_k<<<NUM_EDGES * 16 / 256, 256, 0, stream>>>(off, idx, cnt, Xp, Y);
  node_gather_k<<<NUM_NODES * 16 / 256, 256, 0, stream>>>(off, idx, cnt, Y, Out);
}

// Round 6
// 308.287 us; speedup vs baseline: 7.6659x; 1.3637x over previous
//
#include <hip/hip_runtime.h>
#include <hip/hip_bf16.h>

#define NUM_NODES 100000
#define NUM_EDGES 100000
#define NNZ       1600000
#define D         64

#define N2 (NUM_EDGES + NUM_NODES)          // 200000 concatenated targets

#define BKT     128                          // targets per bucket
#define NBKT_E  ((NUM_EDGES + BKT - 1) / BKT)   // 782
#define NBKT_V  ((NUM_NODES + BKT - 1) / BKT)   // 782
#define NBKT_TOT (NBKT_E + NBKT_V)              // 1564
#define SEG_CAP 3072                         // LDS staging capacity (mean 2048)

#define TILE 8192                            // entries per bin tile
#define NT_SIDE ((NNZ + TILE - 1) / TILE)    // 196 tiles per side
#define TILE_H 4096                          // entries per hist tile (both sides)
#define NT_H ((NNZ + TILE_H - 1) / TILE_H)   // 391

// ---------------------------------------------------------------------------
// Kernel 1: Xp = X @ W^T + b
// ---------------------------------------------------------------------------
#define GEMM_ROWS 32
__global__ __launch_bounds__(256) void gemm_xw(
    const float* __restrict__ X, const float* __restrict__ W,
    const float* __restrict__ b, float* __restrict__ Xp) {
  __shared__ float Wl[D][D + 1];
  __shared__ float Xl[GEMM_ROWS][D];
  const int t = threadIdx.x;

  for (int j = t; j < D * D; j += 256) Wl[j >> 6][j & 63] = W[j];
  const int row0 = blockIdx.x * GEMM_ROWS;
  const float4* X4 = (const float4*)(X + (size_t)row0 * D);
  float4* Xl4 = (float4*)&Xl[0][0];
  for (int j = t; j < GEMM_ROWS * (D / 4); j += 256) Xl4[j] = X4[j];
  __syncthreads();

  const int c = t & 63;
  const int rq = t >> 6;
  float acc[8];
#pragma unroll
  for (int i = 0; i < 8; ++i) acc[i] = 0.f;
#pragma unroll
  for (int k = 0; k < D; ++k) {
    const float w = Wl[c][k];
#pragma unroll
    for (int i = 0; i < 8; ++i) acc[i] = fmaf(Xl[rq + i * 4][k], w, acc[i]);
  }
  const float bias = b[c];
#pragma unroll
  for (int i = 0; i < 8; ++i) {
    const int r = row0 + rq + i * 4;
    Xp[(size_t)r * D + c] = acc[i] + bias;
  }
}

// ---------------------------------------------------------------------------
// Kernel 2: bucket-level histogram via LDS; <=1564 global atomics per block.
// Replaces the 200K-counter hist_k (which wrote 100 MB of atomic line evicts).
// ---------------------------------------------------------------------------
__global__ __launch_bounds__(256) void tile_hist_k(
    const int* __restrict__ V, const int* __restrict__ E,
    int* __restrict__ cntb) {
  __shared__ int h[NBKT_TOT];
  const int t = threadIdx.x;
  for (int i = t; i < NBKT_TOT; i += 256) h[i] = 0;
  __syncthreads();
  const int j0 = blockIdx.x * TILE_H;
  const int n = (NNZ - j0 < TILE_H) ? (NNZ - j0) : TILE_H;
  for (int k = t; k < n; k += 256) {
    const int j = j0 + k;
    atomicAdd(&h[E[j] >> 7], 1);
    atomicAdd(&h[NBKT_E + (V[j] >> 7)], 1);
  }
  __syncthreads();
  for (int i = t; i < NBKT_TOT; i += 256) {
    const int c = h[i];
    if (c) atomicAdd(&cntb[i], c);
  }
}

// ---------------------------------------------------------------------------
// Kernel 3: exclusive scan of cntb[1564] -> bktoff[1565], curb = bktoff
// ---------------------------------------------------------------------------
__global__ __launch_bounds__(256) void scan_bkt_k(
    const int* __restrict__ cntb, int* __restrict__ bktoff,
    int* __restrict__ curb) {
  __shared__ int part[256];
  const int t = threadIdx.x;
  int loc[7];
  int s = 0;
#pragma unroll
  for (int j = 0; j < 7; ++j) {
    const int i = t * 7 + j;
    const int v = (i < NBKT_TOT) ? cntb[i] : 0;
    loc[j] = s;
    s += v;
  }
  part[t] = s;
  __syncthreads();
  for (int st = 1; st < 256; st <<= 1) {
    const int v = part[t];
    const int add = (t >= st) ? part[t - st] : 0;
    __syncthreads();
    part[t] = v + add;
    __syncthreads();
  }
  const int base = (t == 0) ? 0 : part[t - 1];
#pragma unroll
  for (int j = 0; j < 7; ++j) {
    const int i = t * 7 + j;
    if (i < NBKT_TOT) {
      const int o = base + loc[j];
      bktoff[i] = o;
      curb[i] = o;
    }
  }
  if (t == 255) bktoff[NBKT_TOT] = part[255];   // = 2*NNZ
}

// ---------------------------------------------------------------------------
// Kernel 4: tile-local counting sort + bulk-reserved contiguous write-out.
// (round-5 proven: one cursor atomic per tile-bucket, contiguous runs)
// ---------------------------------------------------------------------------
__global__ __launch_bounds__(256) void bin_tile_k(
    const int* __restrict__ V, const int* __restrict__ E,
    int* __restrict__ curb, unsigned* __restrict__ pair) {
  __shared__ unsigned stage[TILE];            // 32 KB
  __shared__ unsigned short bkt16[TILE];      // 16 KB
  __shared__ int hist[NBKT_E];
  __shared__ int gbase[NBKT_E];
  __shared__ int lcur[NBKT_E];
  __shared__ int part[256];

  const int t = threadIdx.x;
  const int side = (blockIdx.x >= NT_SIDE) ? 1 : 0;
  const int bt = blockIdx.x - side * NT_SIDE;
  const int j0 = bt * TILE;
  const int n = (NNZ - j0 < TILE) ? (NNZ - j0) : TILE;
  const int cbase = side ? NBKT_E : 0;

  for (int i = t; i < NBKT_E; i += 256) hist[i] = 0;
  __syncthreads();

  for (int k = 0; k < TILE / 256; ++k) {
    const int j = j0 + t + k * 256;
    if (j - j0 < n) {
      const int key = side ? V[j] : E[j];
      atomicAdd(&hist[key >> 7], 1);
    }
  }
  __syncthreads();

  int loc[4], cnt4[4];
  int s = 0;
#pragma unroll
  for (int u = 0; u < 4; ++u) {
    const int i = t * 4 + u;
    const int v = (i < NBKT_E) ? hist[i] : 0;
    cnt4[u] = v;
    loc[u] = s;
    s += v;
  }
  part[t] = s;
  __syncthreads();
  for (int st = 1; st < 256; st <<= 1) {
    const int v = part[t];
    const int add = (t >= st) ? part[t - st] : 0;
    __syncthreads();
    part[t] = v + add;
    __syncthreads();
  }
  const int base = (t == 0) ? 0 : part[t - 1];
#pragma unroll
  for (int u = 0; u < 4; ++u) {
    const int i = t * 4 + u;
    if (i < NBKT_E) {
      const int o = base + loc[u];
      hist[i] = o;
      lcur[i] = o;
      gbase[i] = cnt4[u] ? atomicAdd(&curb[cbase + i], cnt4[u]) : 0;
    }
  }
  __syncthreads();

  for (int k = 0; k < TILE / 256; ++k) {
    const int j = j0 + t + k * 256;
    if (j - j0 < n) {
      const int v = V[j], e = E[j];
      const int key = side ? v : e;
      const int src = side ? e : v;
      const int b = key >> 7;
      const unsigned w = ((unsigned)src << 7) | (unsigned)(key & 127);
      const int pos = atomicAdd(&lcur[b], 1);
      stage[pos] = w;
      bkt16[pos] = (unsigned short)b;
    }
  }
  __syncthreads();

  for (int sI = t; sI < n; sI += 256) {
    const int b = bkt16[sI];
    pair[gbase[b] + (sI - hist[b])] = stage[sI];
  }
}

// ---------------------------------------------------------------------------
// Kernel 5: per-bucket CSR placement IN PLACE + per-target off/cnt emission.
// Row counts are derived locally from the segment (hist_k is gone).
// ---------------------------------------------------------------------------
__global__ __launch_bounds__(256) void fill_local_k(
    const int* __restrict__ bktoff, unsigned* __restrict__ pair,
    int* __restrict__ off, int* __restrict__ cnt) {
  __shared__ unsigned seg[SEG_CAP];
  __shared__ int rcnt[BKT];
  __shared__ int sc[BKT];
  __shared__ int lcur[BKT];
  const int b = blockIdx.x, t = threadIdx.x;
  int ct0, nrows;
  if (b < NBKT_E) {
    const int e0 = b * BKT;
    ct0 = e0;
    nrows = (NUM_EDGES - e0 < BKT) ? (NUM_EDGES - e0) : BKT;
  } else {
    const int v0 = (b - NBKT_E) * BKT;
    ct0 = NUM_EDGES + v0;
    nrows = (NUM_NODES - v0 < BKT) ? (NUM_NODES - v0) : BKT;
  }
  const int beg = bktoff[b], end = bktoff[b + 1];
  const int n = end - beg;

  if (t < BKT) rcnt[t] = 0;
  __syncthreads();

  const int ncap = (n < SEG_CAP) ? n : SEG_CAP;
  for (int j = t; j < ncap; j += 256) {
    const unsigned w = pair[beg + j];
    seg[j] = w;
    atomicAdd(&rcnt[w & 127u], 1);
  }
  unsigned ex[4];
  int nex = 0;
  for (int j = SEG_CAP + t; j < n; j += 256)
    if (nex < 4) ex[nex++] = pair[beg + j];
  for (int u = 0; u < nex; ++u) atomicAdd(&rcnt[ex[u] & 127u], 1);
  __syncthreads();

  // exclusive scan of the 128 row counts (Hillis-Steele, t<128 active)
  if (t < BKT) sc[t] = rcnt[t];
  __syncthreads();
  for (int st = 1; st < BKT; st <<= 1) {
    int v = 0;
    if (t < BKT) v = (t >= st) ? sc[t - st] + sc[t] : sc[t];
    __syncthreads();
    if (t < BKT) sc[t] = v;
    __syncthreads();
  }
  if (t < BKT) {
    const int o = beg + sc[t] - rcnt[t];   // exclusive
    lcur[t] = o;
    if (t < nrows) {
      off[ct0 + t] = o;
      cnt[ct0 + t] = rcnt[t];
    }
  }
  if (b == NBKT_TOT - 1 && t == 0) off[N2] = end;
  __syncthreads();

  int* idx = (int*)pair;
  for (int j = t; j < ncap; j += 256) {
    const unsigned w = seg[j];
    const int pos = atomicAdd(&lcur[w & 127u], 1);
    idx[pos] = (int)(w >> 7);
  }
  for (int u = 0; u < nex; ++u) {
    const unsigned w = ex[u];
    const int pos = atomicAdd(&lcur[w & 127u], 1);
    idx[pos] = (int)(w >> 7);
  }
}

// ---------------------------------------------------------------------------
// Kernel 6: per-edge gather (16 lanes/edge, float4/lane, register acc).
// ---------------------------------------------------------------------------
__global__ __launch_bounds__(256) void edge_gather_k(
    const int* __restrict__ off, const int* __restrict__ idx,
    const int* __restrict__ cnt, const float* __restrict__ Xp,
    float* __restrict__ Y) {
  const int g = blockIdx.x * blockDim.x + threadIdx.x;
  const int e = g >> 4, q = g & 15;
  if (e >= NUM_EDGES) return;
  const int beg = off[e], end = off[e + 1];
  const float4* Xp4 = (const float4*)Xp;
  float4 acc = make_float4(0.f, 0.f, 0.f, 0.f);
  float dsum = 0.f;
  int m = beg;
  for (; m + 1 < end; m += 2) {
    const int v0 = idx[m], v1 = idx[m + 1];
    const float4 x0 = Xp4[v0 * 16 + q];
    const float4 x1 = Xp4[v1 * 16 + q];
    const float d0 = (float)cnt[NUM_EDGES + v0];
    const float d1 = (float)cnt[NUM_EDGES + v1];
    acc.x += x0.x + x1.x; acc.y += x0.y + x1.y;
    acc.z += x0.z + x1.z; acc.w += x0.w + x1.w;
    dsum += d0 + d1;
  }
  if (m < end) {
    const int v = idx[m];
    const float4 x = Xp4[v * 16 + q];
    acc.x += x.x; acc.y += x.y; acc.z += x.z; acc.w += x.w;
    dsum += (float)cnt[NUM_EDGES + v];
  }
  const float ce = (float)(end - beg);
  const float De = dsum / (ce + 1.f);
  const float inv = (De > 0.f) ? rsqrtf(fmaxf(De, 1e-30f)) : 1.f;
  const float s = inv / fmaxf(ce, 1.f);
  ((float4*)Y)[e * 16 + q] = make_float4(acc.x * s, acc.y * s, acc.z * s, acc.w * s);
}

// ---------------------------------------------------------------------------
// Kernel 7: per-node gather.  Out[v,:] = Dv_inv * sum_e Y[e,:]
// ---------------------------------------------------------------------------
__global__ __launch_bounds__(256) void node_gather_k(
    const int* __restrict__ off, const int* __restrict__ idx,
    const int* __restrict__ cnt, const float* __restrict__ Y,
    float* __restrict__ Out) {
  const int g = blockIdx.x * blockDim.x + threadIdx.x;
  const int v = g >> 4, q = g & 15;
  if (v >= NUM_NODES) return;
  const int beg = off[NUM_EDGES + v], end = off[NUM_EDGES + v + 1];
  const float4* Y4 = (const float4*)Y;
  float4 acc = make_float4(0.f, 0.f, 0.f, 0.f);
  int m = beg;
  for (; m + 1 < end; m += 2) {
    const int e0 = idx[m], e1 = idx[m + 1];
    const float4 y0 = Y4[e0 * 16 + q];
    const float4 y1 = Y4[e1 * 16 + q];
    acc.x += y0.x + y1.x; acc.y += y0.y + y1.y;
    acc.z += y0.z + y1.z; acc.w += y0.w + y1.w;
  }
  if (m < end) {
    const float4 y = Y4[idx[m] * 16 + q];
    acc.x += y.x; acc.y += y.y; acc.z += y.z; acc.w += y.w;
  }
  const float d = (float)cnt[NUM_EDGES + v];
  const float s = (d > 0.f) ? rsqrtf(d) : 0.f;
  ((float4*)Out)[v * 16 + q] = make_float4(acc.x * s, acc.y * s, acc.z * s, acc.w * s);
}

extern "C" void kernel_launch(void* const* d_in, const int* in_sizes, int n_in,
                              void* d_out, int out_size, void* d_ws, size_t ws_size,
                              hipStream_t stream) {
  const float* X = (const float*)d_in[0];
  const int*   V = (const int*)d_in[1];
  const int*   E = (const int*)d_in[2];
  const float* W = (const float*)d_in[4];
  const float* b = (const float*)d_in[5];
  float* Out = (float*)d_out;

  // workspace layout (~65.7 MB)
  float*    Xp     = (float*)d_ws;                       // 25.6 MB
  float*    Y      = Xp + (size_t)NUM_NODES * D;         // 25.6 MB
  int*      cntb   = (int*)(Y + (size_t)NUM_EDGES * D);  // 1564
  int*      bktoff = cntb + NBKT_TOT;                    // 1565
  int*      curb   = bktoff + NBKT_TOT + 1;              // 1564
  int*      off    = curb + NBKT_TOT;                    // N2+1 (800 KB)
  int*      cnt    = off + N2 + 1;                       // N2   (800 KB)
  unsigned* pair   = (unsigned*)(cnt + N2);              // 2*NNZ = 12.8 MB
  int*      idx    = (int*)pair;                         // in-place CSR result

  hipMemsetAsync(cntb, 0, (size_t)NBKT_TOT * sizeof(int), stream);

  gemm_xw<<<NUM_NODES / GEMM_ROWS, 256, 0, stream>>>(X, W, b, Xp);
  tile_hist_k<<<NT_H, 256, 0, stream>>>(V, E, cntb);
  scan_bkt_k<<<1, 256, 0, stream>>>(cntb, bktoff, curb);
  bin_tile_k<<<2 * NT_SIDE, 256, 0, stream>>>(V, E, curb, pair);
  fill_local_k<<<NBKT_TOT, 256, 0, stream>>>(bktoff, pair, off, cnt);
  edge_gather_k<<<NUM_EDGES * 16 / 256, 256, 0, stream>>>(off, idx, cnt, Xp, Y);
  node_gather_k<<<NUM_NODES * 16 / 256, 256, 0, stream>>>(off, idx, cnt, Y, Out);
}

// Round 7
// 273.942 us; speedup vs baseline: 8.6270x; 1.1254x over previous
//
#include <hip/hip_runtime.h>
#include <hip/hip_bf16.h>

#define NUM_NODES 100000
#define NUM_EDGES 100000
#define NNZ       1600000
#define D         64

#define N2 (NUM_EDGES + NUM_NODES)          // 200000 concatenated targets

#define BKT     128                          // targets per bucket
#define NBKT_E  ((NUM_EDGES + BKT - 1) / BKT)   // 782
#define NBKT_V  ((NUM_NODES + BKT - 1) / BKT)   // 782
#define NBKT_TOT (NBKT_E + NBKT_V)              // 1564
#define SEG_CAP 3072                         // LDS staging capacity (mean 2048)

#define TILE 8192                            // entries per bin tile
#define NT_SIDE ((NNZ + TILE - 1) / TILE)    // 196 tiles per side
#define TILE_H 4096                          // entries per hist tile (both sides)
#define NT_H ((NNZ + TILE_H - 1) / TILE_H)   // 391

// ---- bf16 helpers (RNE pack, shift unpack) --------------------------------
__device__ inline unsigned pack_bf16x2(float a, float b) {
  unsigned ua = __float_as_uint(a), ub = __float_as_uint(b);
  ua = (ua + 0x7fffu + ((ua >> 16) & 1u)) >> 16;
  ub = (ub + 0x7fffu + ((ub >> 16) & 1u)) >> 16;
  return ua | (ub << 16);
}
__device__ inline void unpack_acc(unsigned u, float& lo, float& hi) {
  lo = __uint_as_float(u << 16);
  hi = __uint_as_float(u & 0xffff0000u);
}

// ---------------------------------------------------------------------------
// Kernel 1: Xp = bf16(X @ W^T + b)
// ---------------------------------------------------------------------------
#define GEMM_ROWS 32
__global__ __launch_bounds__(256) void gemm_xw(
    const float* __restrict__ X, const float* __restrict__ W,
    const float* __restrict__ b, unsigned short* __restrict__ Xpb) {
  __shared__ float Wl[D][D + 1];
  __shared__ float Xl[GEMM_ROWS][D];
  const int t = threadIdx.x;

  for (int j = t; j < D * D; j += 256) Wl[j >> 6][j & 63] = W[j];
  const int row0 = blockIdx.x * GEMM_ROWS;
  const float4* X4 = (const float4*)(X + (size_t)row0 * D);
  float4* Xl4 = (float4*)&Xl[0][0];
  for (int j = t; j < GEMM_ROWS * (D / 4); j += 256) Xl4[j] = X4[j];
  __syncthreads();

  const int c = t & 63;
  const int rq = t >> 6;
  float acc[8];
#pragma unroll
  for (int i = 0; i < 8; ++i) acc[i] = 0.f;
#pragma unroll
  for (int k = 0; k < D; ++k) {
    const float w = Wl[c][k];
#pragma unroll
    for (int i = 0; i < 8; ++i) acc[i] = fmaf(Xl[rq + i * 4][k], w, acc[i]);
  }
  const float bias = b[c];
#pragma unroll
  for (int i = 0; i < 8; ++i) {
    const int r = row0 + rq + i * 4;
    const float v = acc[i] + bias;
    unsigned u = __float_as_uint(v);
    u = (u + 0x7fffu + ((u >> 16) & 1u)) >> 16;
    Xpb[(size_t)r * D + c] = (unsigned short)u;
  }
}

// ---------------------------------------------------------------------------
// Kernel 2: bucket-level histogram via LDS (round-6 proven)
// ---------------------------------------------------------------------------
__global__ __launch_bounds__(256) void tile_hist_k(
    const int* __restrict__ V, const int* __restrict__ E,
    int* __restrict__ cntb) {
  __shared__ int h[NBKT_TOT];
  const int t = threadIdx.x;
  for (int i = t; i < NBKT_TOT; i += 256) h[i] = 0;
  __syncthreads();
  const int j0 = blockIdx.x * TILE_H;
  const int n = (NNZ - j0 < TILE_H) ? (NNZ - j0) : TILE_H;
  for (int k = t; k < n; k += 256) {
    const int j = j0 + k;
    atomicAdd(&h[E[j] >> 7], 1);
    atomicAdd(&h[NBKT_E + (V[j] >> 7)], 1);
  }
  __syncthreads();
  for (int i = t; i < NBKT_TOT; i += 256) {
    const int c = h[i];
    if (c) atomicAdd(&cntb[i], c);
  }
}

// ---------------------------------------------------------------------------
// Kernel 3: exclusive scan of cntb[1564] -> bktoff[1565], curb = bktoff
// ---------------------------------------------------------------------------
__global__ __launch_bounds__(256) void scan_bkt_k(
    const int* __restrict__ cntb, int* __restrict__ bktoff,
    int* __restrict__ curb) {
  __shared__ int part[256];
  const int t = threadIdx.x;
  int loc[7];
  int s = 0;
#pragma unroll
  for (int j = 0; j < 7; ++j) {
    const int i = t * 7 + j;
    const int v = (i < NBKT_TOT) ? cntb[i] : 0;
    loc[j] = s;
    s += v;
  }
  part[t] = s;
  __syncthreads();
  for (int st = 1; st < 256; st <<= 1) {
    const int v = part[t];
    const int add = (t >= st) ? part[t - st] : 0;
    __syncthreads();
    part[t] = v + add;
    __syncthreads();
  }
  const int base = (t == 0) ? 0 : part[t - 1];
#pragma unroll
  for (int j = 0; j < 7; ++j) {
    const int i = t * 7 + j;
    if (i < NBKT_TOT) {
      const int o = base + loc[j];
      bktoff[i] = o;
      curb[i] = o;
    }
  }
  if (t == 255) bktoff[NBKT_TOT] = part[255];   // = 2*NNZ
}

// ---------------------------------------------------------------------------
// Kernel 4: tile-local counting sort + bulk-reserved contiguous write-out
// (round-5 proven)
// ---------------------------------------------------------------------------
__global__ __launch_bounds__(256) void bin_tile_k(
    const int* __restrict__ V, const int* __restrict__ E,
    int* __restrict__ curb, unsigned* __restrict__ pair) {
  __shared__ unsigned stage[TILE];            // 32 KB
  __shared__ unsigned short bkt16[TILE];      // 16 KB
  __shared__ int hist[NBKT_E];
  __shared__ int gbase[NBKT_E];
  __shared__ int lcur[NBKT_E];
  __shared__ int part[256];

  const int t = threadIdx.x;
  const int side = (blockIdx.x >= NT_SIDE) ? 1 : 0;
  const int bt = blockIdx.x - side * NT_SIDE;
  const int j0 = bt * TILE;
  const int n = (NNZ - j0 < TILE) ? (NNZ - j0) : TILE;
  const int cbase = side ? NBKT_E : 0;

  for (int i = t; i < NBKT_E; i += 256) hist[i] = 0;
  __syncthreads();

  for (int k = 0; k < TILE / 256; ++k) {
    const int j = j0 + t + k * 256;
    if (j - j0 < n) {
      const int key = side ? V[j] : E[j];
      atomicAdd(&hist[key >> 7], 1);
    }
  }
  __syncthreads();

  int loc[4], cnt4[4];
  int s = 0;
#pragma unroll
  for (int u = 0; u < 4; ++u) {
    const int i = t * 4 + u;
    const int v = (i < NBKT_E) ? hist[i] : 0;
    cnt4[u] = v;
    loc[u] = s;
    s += v;
  }
  part[t] = s;
  __syncthreads();
  for (int st = 1; st < 256; st <<= 1) {
    const int v = part[t];
    const int add = (t >= st) ? part[t - st] : 0;
    __syncthreads();
    part[t] = v + add;
    __syncthreads();
  }
  const int base = (t == 0) ? 0 : part[t - 1];
#pragma unroll
  for (int u = 0; u < 4; ++u) {
    const int i = t * 4 + u;
    if (i < NBKT_E) {
      const int o = base + loc[u];
      hist[i] = o;
      lcur[i] = o;
      gbase[i] = cnt4[u] ? atomicAdd(&curb[cbase + i], cnt4[u]) : 0;
    }
  }
  __syncthreads();

  for (int k = 0; k < TILE / 256; ++k) {
    const int j = j0 + t + k * 256;
    if (j - j0 < n) {
      const int v = V[j], e = E[j];
      const int key = side ? v : e;
      const int src = side ? e : v;
      const int b = key >> 7;
      const unsigned w = ((unsigned)src << 7) | (unsigned)(key & 127);
      const int pos = atomicAdd(&lcur[b], 1);
      stage[pos] = w;
      bkt16[pos] = (unsigned short)b;
    }
  }
  __syncthreads();

  for (int sI = t; sI < n; sI += 256) {
    const int b = bkt16[sI];
    pair[gbase[b] + (sI - hist[b])] = stage[sI];
  }
}

// ---------------------------------------------------------------------------
// Kernel 5: per-bucket CSR placement IN PLACE + per-target off/cnt emission
// (round-6 proven)
// ---------------------------------------------------------------------------
__global__ __launch_bounds__(256) void fill_local_k(
    const int* __restrict__ bktoff, unsigned* __restrict__ pair,
    int* __restrict__ off, int* __restrict__ cnt) {
  __shared__ unsigned seg[SEG_CAP];
  __shared__ int rcnt[BKT];
  __shared__ int sc[BKT];
  __shared__ int lcur[BKT];
  const int b = blockIdx.x, t = threadIdx.x;
  int ct0, nrows;
  if (b < NBKT_E) {
    const int e0 = b * BKT;
    ct0 = e0;
    nrows = (NUM_EDGES - e0 < BKT) ? (NUM_EDGES - e0) : BKT;
  } else {
    const int v0 = (b - NBKT_E) * BKT;
    ct0 = NUM_EDGES + v0;
    nrows = (NUM_NODES - v0 < BKT) ? (NUM_NODES - v0) : BKT;
  }
  const int beg = bktoff[b], end = bktoff[b + 1];
  const int n = end - beg;

  if (t < BKT) rcnt[t] = 0;
  __syncthreads();

  const int ncap = (n < SEG_CAP) ? n : SEG_CAP;
  for (int j = t; j < ncap; j += 256) {
    const unsigned w = pair[beg + j];
    seg[j] = w;
    atomicAdd(&rcnt[w & 127u], 1);
  }
  unsigned ex[4];
  int nex = 0;
  for (int j = SEG_CAP + t; j < n; j += 256)
    if (nex < 4) ex[nex++] = pair[beg + j];
  for (int u = 0; u < nex; ++u) atomicAdd(&rcnt[ex[u] & 127u], 1);
  __syncthreads();

  if (t < BKT) sc[t] = rcnt[t];
  __syncthreads();
  for (int st = 1; st < BKT; st <<= 1) {
    int v = 0;
    if (t < BKT) v = (t >= st) ? sc[t - st] + sc[t] : sc[t];
    __syncthreads();
    if (t < BKT) sc[t] = v;
    __syncthreads();
  }
  if (t < BKT) {
    const int o = beg + sc[t] - rcnt[t];   // exclusive
    lcur[t] = o;
    if (t < nrows) {
      off[ct0 + t] = o;
      cnt[ct0 + t] = rcnt[t];
    }
  }
  if (b == NBKT_TOT - 1 && t == 0) off[N2] = end;
  __syncthreads();

  int* idx = (int*)pair;
  for (int j = t; j < ncap; j += 256) {
    const unsigned w = seg[j];
    const int pos = atomicAdd(&lcur[w & 127u], 1);
    idx[pos] = (int)(w >> 7);
  }
  for (int u = 0; u < nex; ++u) {
    const unsigned w = ex[u];
    const int pos = atomicAdd(&lcur[w & 127u], 1);
    idx[pos] = (int)(w >> 7);
  }
}

// ---------------------------------------------------------------------------
// Kernel 6: per-edge gather on bf16 rows. 8 lanes/edge, uint4 = 8 bf16/lane.
// fp32 accumulate; fused De/cnt normalization; bf16 row write.
// ---------------------------------------------------------------------------
__global__ __launch_bounds__(256) void edge_gather_k(
    const int* __restrict__ off, const int* __restrict__ idx,
    const int* __restrict__ cnt, const uint4* __restrict__ Xpb,
    uint4* __restrict__ Yb) {
  const int g = blockIdx.x * blockDim.x + threadIdx.x;
  const int e = g >> 3, q = g & 7;
  if (e >= NUM_EDGES) return;
  const int beg = off[e], end = off[e + 1];
  float acc[8];
#pragma unroll
  for (int i = 0; i < 8; ++i) acc[i] = 0.f;
  float dsum = 0.f;
  for (int m = beg; m < end; ++m) {
    const int v = idx[m];
    const uint4 w = Xpb[v * 8 + q];
    dsum += (float)cnt[NUM_EDGES + v];
    float lo, hi;
    unpack_acc(w.x, lo, hi); acc[0] += lo; acc[1] += hi;
    unpack_acc(w.y, lo, hi); acc[2] += lo; acc[3] += hi;
    unpack_acc(w.z, lo, hi); acc[4] += lo; acc[5] += hi;
    unpack_acc(w.w, lo, hi); acc[6] += lo; acc[7] += hi;
  }
  const float ce = (float)(end - beg);
  const float De = dsum / (ce + 1.f);
  const float inv = (De > 0.f) ? rsqrtf(fmaxf(De, 1e-30f)) : 1.f;
  const float s = inv / fmaxf(ce, 1.f);
  uint4 o;
  o.x = pack_bf16x2(acc[0] * s, acc[1] * s);
  o.y = pack_bf16x2(acc[2] * s, acc[3] * s);
  o.z = pack_bf16x2(acc[4] * s, acc[5] * s);
  o.w = pack_bf16x2(acc[6] * s, acc[7] * s);
  Yb[e * 8 + q] = o;
}

// ---------------------------------------------------------------------------
// Kernel 7: per-node gather on bf16 Y rows; fp32 output.
// ---------------------------------------------------------------------------
__global__ __launch_bounds__(256) void node_gather_k(
    const int* __restrict__ off, const int* __restrict__ idx,
    const int* __restrict__ cnt, const uint4* __restrict__ Yb,
    float* __restrict__ Out) {
  const int g = blockIdx.x * blockDim.x + threadIdx.x;
  const int v = g >> 3, q = g & 7;
  if (v >= NUM_NODES) return;
  const int beg = off[NUM_EDGES + v], end = off[NUM_EDGES + v + 1];
  float acc[8];
#pragma unroll
  for (int i = 0; i < 8; ++i) acc[i] = 0.f;
  for (int m = beg; m < end; ++m) {
    const int e = idx[m];
    const uint4 w = Yb[e * 8 + q];
    float lo, hi;
    unpack_acc(w.x, lo, hi); acc[0] += lo; acc[1] += hi;
    unpack_acc(w.y, lo, hi); acc[2] += lo; acc[3] += hi;
    unpack_acc(w.z, lo, hi); acc[4] += lo; acc[5] += hi;
    unpack_acc(w.w, lo, hi); acc[6] += lo; acc[7] += hi;
  }
  const float d = (float)cnt[NUM_EDGES + v];
  const float s = (d > 0.f) ? rsqrtf(d) : 0.f;
  float4* O4 = (float4*)(Out + (size_t)v * D + q * 8);
  O4[0] = make_float4(acc[0] * s, acc[1] * s, acc[2] * s, acc[3] * s);
  O4[1] = make_float4(acc[4] * s, acc[5] * s, acc[6] * s, acc[7] * s);
}

extern "C" void kernel_launch(void* const* d_in, const int* in_sizes, int n_in,
                              void* d_out, int out_size, void* d_ws, size_t ws_size,
                              hipStream_t stream) {
  const float* X = (const float*)d_in[0];
  const int*   V = (const int*)d_in[1];
  const int*   E = (const int*)d_in[2];
  const float* W = (const float*)d_in[4];
  const float* b = (const float*)d_in[5];
  float* Out = (float*)d_out;

  // workspace layout (~41 MB)
  unsigned short* Xpb = (unsigned short*)d_ws;                 // 12.8 MB bf16
  unsigned short* Ybu = Xpb + (size_t)NUM_NODES * D;           // 12.8 MB bf16
  int*      cntb   = (int*)(Ybu + (size_t)NUM_EDGES * D);      // 1564
  int*      bktoff = cntb + NBKT_TOT;                          // 1565
  int*      curb   = bktoff + NBKT_TOT + 1;                    // 1564
  int*      off    = curb + NBKT_TOT;                          // N2+1 (800 KB)
  int*      cnt    = off + N2 + 1;                             // N2   (800 KB)
  unsigned* pair   = (unsigned*)(cnt + N2);                    // 2*NNZ = 12.8 MB
  int*      idx    = (int*)pair;                               // in-place CSR

  hipMemsetAsync(cntb, 0, (size_t)NBKT_TOT * sizeof(int), stream);

  gemm_xw<<<NUM_NODES / GEMM_ROWS, 256, 0, stream>>>(X, W, b, Xpb);
  tile_hist_k<<<NT_H, 256, 0, stream>>>(V, E, cntb);
  scan_bkt_k<<<1, 256, 0, stream>>>(cntb, bktoff, curb);
  bin_tile_k<<<2 * NT_SIDE, 256, 0, stream>>>(V, E, curb, pair);
  fill_local_k<<<NBKT_TOT, 256, 0, stream>>>(bktoff, pair, off, cnt);
  edge_gather_k<<<NUM_EDGES * 8 / 256, 256, 0, stream>>>(
      off, idx, cnt, (const uint4*)Xpb, (uint4*)Ybu);
  node_gather_k<<<NUM_NODES * 8 / 256, 256, 0, stream>>>(
      off, idx, cnt, (const uint4*)Ybu, Out);
}

// Round 8
// 257.399 us; speedup vs baseline: 9.1815x; 1.0643x over previous
//
#include <hip/hip_runtime.h>
#include <hip/hip_bf16.h>

#define NUM_NODES 100000
#define NUM_EDGES 100000
#define NNZ       1600000
#define D         64

#define N2 (NUM_EDGES + NUM_NODES)          // 200000 concatenated targets

#define BKT     128                          // targets per bucket
#define NBKT_E  ((NUM_EDGES + BKT - 1) / BKT)   // 782
#define NBKT_V  ((NUM_NODES + BKT - 1) / BKT)   // 782
#define NBKT_TOT (NBKT_E + NBKT_V)              // 1564
#define SEG_CAP 3072                         // LDS staging capacity (mean 2048)

#define TILE 8192                            // entries per bin tile
#define NT_SIDE ((NNZ + TILE - 1) / TILE)    // 196 tiles per side
#define TILE_H 4096                          // entries per hist tile (both sides)
#define NT_H ((NNZ + TILE_H - 1) / TILE_H)   // 391

// ---- bf16 helpers (RNE pack, shift unpack) --------------------------------
__device__ inline unsigned pack_bf16x2(float a, float b) {
  unsigned ua = __float_as_uint(a), ub = __float_as_uint(b);
  ua = (ua + 0x7fffu + ((ua >> 16) & 1u)) >> 16;
  ub = (ub + 0x7fffu + ((ub >> 16) & 1u)) >> 16;
  return ua | (ub << 16);
}
__device__ inline void unpack_acc(unsigned u, float& lo, float& hi) {
  lo = __uint_as_float(u << 16);
  hi = __uint_as_float(u & 0xffff0000u);
}

// ---------------------------------------------------------------------------
// Kernel 1: Xp = bf16(X @ W^T + b)
// ---------------------------------------------------------------------------
#define GEMM_ROWS 32
__global__ __launch_bounds__(256) void gemm_xw(
    const float* __restrict__ X, const float* __restrict__ W,
    const float* __restrict__ b, unsigned short* __restrict__ Xpb) {
  __shared__ float Wl[D][D + 1];
  __shared__ float Xl[GEMM_ROWS][D];
  const int t = threadIdx.x;

  for (int j = t; j < D * D; j += 256) Wl[j >> 6][j & 63] = W[j];
  const int row0 = blockIdx.x * GEMM_ROWS;
  const float4* X4 = (const float4*)(X + (size_t)row0 * D);
  float4* Xl4 = (float4*)&Xl[0][0];
  for (int j = t; j < GEMM_ROWS * (D / 4); j += 256) Xl4[j] = X4[j];
  __syncthreads();

  const int c = t & 63;
  const int rq = t >> 6;
  float acc[8];
#pragma unroll
  for (int i = 0; i < 8; ++i) acc[i] = 0.f;
#pragma unroll
  for (int k = 0; k < D; ++k) {
    const float w = Wl[c][k];
#pragma unroll
    for (int i = 0; i < 8; ++i) acc[i] = fmaf(Xl[rq + i * 4][k], w, acc[i]);
  }
  const float bias = b[c];
#pragma unroll
  for (int i = 0; i < 8; ++i) {
    const int r = row0 + rq + i * 4;
    const float v = acc[i] + bias;
    unsigned u = __float_as_uint(v);
    u = (u + 0x7fffu + ((u >> 16) & 1u)) >> 16;
    Xpb[(size_t)r * D + c] = (unsigned short)u;
  }
}

// ---------------------------------------------------------------------------
// Kernel 2: bucket-level histogram via LDS (round-6 proven)
// ---------------------------------------------------------------------------
__global__ __launch_bounds__(256) void tile_hist_k(
    const int* __restrict__ V, const int* __restrict__ E,
    int* __restrict__ cntb) {
  __shared__ int h[NBKT_TOT];
  const int t = threadIdx.x;
  for (int i = t; i < NBKT_TOT; i += 256) h[i] = 0;
  __syncthreads();
  const int j0 = blockIdx.x * TILE_H;
  const int n = (NNZ - j0 < TILE_H) ? (NNZ - j0) : TILE_H;
  for (int k = t; k < n; k += 256) {
    const int j = j0 + k;
    atomicAdd(&h[E[j] >> 7], 1);
    atomicAdd(&h[NBKT_E + (V[j] >> 7)], 1);
  }
  __syncthreads();
  for (int i = t; i < NBKT_TOT; i += 256) {
    const int c = h[i];
    if (c) atomicAdd(&cntb[i], c);
  }
}

// ---------------------------------------------------------------------------
// Kernel 3: exclusive scan of cntb[1564] -> bktoff[1565], curb = bktoff
// ---------------------------------------------------------------------------
__global__ __launch_bounds__(256) void scan_bkt_k(
    const int* __restrict__ cntb, int* __restrict__ bktoff,
    int* __restrict__ curb) {
  __shared__ int part[256];
  const int t = threadIdx.x;
  int loc[7];
  int s = 0;
#pragma unroll
  for (int j = 0; j < 7; ++j) {
    const int i = t * 7 + j;
    const int v = (i < NBKT_TOT) ? cntb[i] : 0;
    loc[j] = s;
    s += v;
  }
  part[t] = s;
  __syncthreads();
  for (int st = 1; st < 256; st <<= 1) {
    const int v = part[t];
    const int add = (t >= st) ? part[t - st] : 0;
    __syncthreads();
    part[t] = v + add;
    __syncthreads();
  }
  const int base = (t == 0) ? 0 : part[t - 1];
#pragma unroll
  for (int j = 0; j < 7; ++j) {
    const int i = t * 7 + j;
    if (i < NBKT_TOT) {
      const int o = base + loc[j];
      bktoff[i] = o;
      curb[i] = o;
    }
  }
  if (t == 255) bktoff[NBKT_TOT] = part[255];   // = 2*NNZ
}

// ---------------------------------------------------------------------------
// Kernel 4: tile-local counting sort + bulk-reserved contiguous write-out.
// v2: 1024 threads/block (4x waves vs round 7's grid-limited 256), bkt16
// dropped — phase 4 recovers the bucket by binary search over hist[] in LDS.
// Sorted (dense) write-out retained: WRITE_SIZE stays ~1.9x payload.
// ---------------------------------------------------------------------------
__global__ __launch_bounds__(1024, 4) void bin_tile_k(
    const int* __restrict__ V, const int* __restrict__ E,
    int* __restrict__ curb, unsigned* __restrict__ pair) {
  __shared__ unsigned stage[TILE];            // 32 KB
  __shared__ int hist[NBKT_E];                // counts -> exclusive offsets
  __shared__ int gbase[NBKT_E];
  __shared__ int lcur[NBKT_E];
  __shared__ int part[1024];

  const int t = threadIdx.x;
  const int side = (blockIdx.x >= NT_SIDE) ? 1 : 0;
  const int bt = blockIdx.x - side * NT_SIDE;
  const int j0 = bt * TILE;
  const int n = (NNZ - j0 < TILE) ? (NNZ - j0) : TILE;
  const int cbase = side ? NBKT_E : 0;

  for (int i = t; i < NBKT_E; i += 1024) hist[i] = 0;
  __syncthreads();

  // phase 1: tile histogram
#pragma unroll
  for (int k = 0; k < TILE / 1024; ++k) {
    const int j = j0 + t + k * 1024;
    if (j - j0 < n) {
      const int key = side ? V[j] : E[j];
      atomicAdd(&hist[key >> 7], 1);
    }
  }
  __syncthreads();

  // phase 2: scan (1 bucket/thread) + one global reservation per bucket
  const int cb = (t < NBKT_E) ? hist[t] : 0;
  part[t] = cb;
  __syncthreads();
  for (int st = 1; st < 1024; st <<= 1) {
    const int x = part[t];
    const int add = (t >= st) ? part[t - st] : 0;
    __syncthreads();
    part[t] = x + add;
    __syncthreads();
  }
  if (t < NBKT_E) {
    const int o = part[t] - cb;   // exclusive local offset
    hist[t] = o;
    lcur[t] = o;
    gbase[t] = cb ? atomicAdd(&curb[cbase + t], cb) : 0;
  }
  __syncthreads();

  // phase 3: local bucket-sort into stage
#pragma unroll
  for (int k = 0; k < TILE / 1024; ++k) {
    const int j = j0 + t + k * 1024;
    if (j - j0 < n) {
      const int v = V[j], e = E[j];
      const int key = side ? v : e;
      const int src = side ? e : v;
      const int b = key >> 7;
      const unsigned w = ((unsigned)src << 7) | (unsigned)(key & 127);
      const int pos = atomicAdd(&lcur[b], 1);
      stage[pos] = w;
    }
  }
  __syncthreads();

  // phase 4: dense write-out; bucket via binary search over hist offsets
  for (int sI = t; sI < n; sI += 1024) {
    int lo = 0, hi = NBKT_E - 1;
    while (lo < hi) {
      const int mid = (lo + hi + 1) >> 1;
      if (hist[mid] <= sI) lo = mid; else hi = mid - 1;
    }
    pair[gbase[lo] + (sI - hist[lo])] = stage[sI];
  }
}

// ---------------------------------------------------------------------------
// Kernel 5: per-bucket CSR placement IN PLACE + per-target off/cnt emission.
// v2: 512 threads (was 256) to halve serial depth.
// ---------------------------------------------------------------------------
__global__ __launch_bounds__(512) void fill_local_k(
    const int* __restrict__ bktoff, unsigned* __restrict__ pair,
    int* __restrict__ off, int* __restrict__ cnt) {
  __shared__ unsigned seg[SEG_CAP];
  __shared__ int rcnt[BKT];
  __shared__ int sc[BKT];
  __shared__ int lcur[BKT];
  const int b = blockIdx.x, t = threadIdx.x;
  int ct0, nrows;
  if (b < NBKT_E) {
    const int e0 = b * BKT;
    ct0 = e0;
    nrows = (NUM_EDGES - e0 < BKT) ? (NUM_EDGES - e0) : BKT;
  } else {
    const int v0 = (b - NBKT_E) * BKT;
    ct0 = NUM_EDGES + v0;
    nrows = (NUM_NODES - v0 < BKT) ? (NUM_NODES - v0) : BKT;
  }
  const int beg = bktoff[b], end = bktoff[b + 1];
  const int n = end - beg;

  if (t < BKT) rcnt[t] = 0;
  __syncthreads();

  const int ncap = (n < SEG_CAP) ? n : SEG_CAP;
  for (int j = t; j < ncap; j += 512) {
    const unsigned w = pair[beg + j];
    seg[j] = w;
    atomicAdd(&rcnt[w & 127u], 1);
  }
  unsigned ex[4];
  int nex = 0;
  for (int j = SEG_CAP + t; j < n; j += 512)
    if (nex < 4) ex[nex++] = pair[beg + j];
  for (int u = 0; u < nex; ++u) atomicAdd(&rcnt[ex[u] & 127u], 1);
  __syncthreads();

  if (t < BKT) sc[t] = rcnt[t];
  __syncthreads();
  for (int st = 1; st < BKT; st <<= 1) {
    int v = 0;
    if (t < BKT) v = (t >= st) ? sc[t - st] + sc[t] : sc[t];
    __syncthreads();
    if (t < BKT) sc[t] = v;
    __syncthreads();
  }
  if (t < BKT) {
    const int o = beg + sc[t] - rcnt[t];   // exclusive
    lcur[t] = o;
    if (t < nrows) {
      off[ct0 + t] = o;
      cnt[ct0 + t] = rcnt[t];
    }
  }
  if (b == NBKT_TOT - 1 && t == 0) off[N2] = end;
  __syncthreads();

  int* idx = (int*)pair;
  for (int j = t; j < ncap; j += 512) {
    const unsigned w = seg[j];
    const int pos = atomicAdd(&lcur[w & 127u], 1);
    idx[pos] = (int)(w >> 7);
  }
  for (int u = 0; u < nex; ++u) {
    const unsigned w = ex[u];
    const int pos = atomicAdd(&lcur[w & 127u], 1);
    idx[pos] = (int)(w >> 7);
  }
}

// ---------------------------------------------------------------------------
// Kernel 6: per-edge gather on bf16 rows. 8 lanes/edge, uint4 = 8 bf16/lane.
// ---------------------------------------------------------------------------
__global__ __launch_bounds__(256) void edge_gather_k(
    const int* __restrict__ off, const int* __restrict__ idx,
    const int* __restrict__ cnt, const uint4* __restrict__ Xpb,
    uint4* __restrict__ Yb) {
  const int g = blockIdx.x * blockDim.x + threadIdx.x;
  const int e = g >> 3, q = g & 7;
  if (e >= NUM_EDGES) return;
  const int beg = off[e], end = off[e + 1];
  float acc[8];
#pragma unroll
  for (int i = 0; i < 8; ++i) acc[i] = 0.f;
  float dsum = 0.f;
  for (int m = beg; m < end; ++m) {
    const int v = idx[m];
    const uint4 w = Xpb[v * 8 + q];
    dsum += (float)cnt[NUM_EDGES + v];
    float lo, hi;
    unpack_acc(w.x, lo, hi); acc[0] += lo; acc[1] += hi;
    unpack_acc(w.y, lo, hi); acc[2] += lo; acc[3] += hi;
    unpack_acc(w.z, lo, hi); acc[4] += lo; acc[5] += hi;
    unpack_acc(w.w, lo, hi); acc[6] += lo; acc[7] += hi;
  }
  const float ce = (float)(end - beg);
  const float De = dsum / (ce + 1.f);
  const float inv = (De > 0.f) ? rsqrtf(fmaxf(De, 1e-30f)) : 1.f;
  const float s = inv / fmaxf(ce, 1.f);
  uint4 o;
  o.x = pack_bf16x2(acc[0] * s, acc[1] * s);
  o.y = pack_bf16x2(acc[2] * s, acc[3] * s);
  o.z = pack_bf16x2(acc[4] * s, acc[5] * s);
  o.w = pack_bf16x2(acc[6] * s, acc[7] * s);
  Yb[e * 8 + q] = o;
}

// ---------------------------------------------------------------------------
// Kernel 7: per-node gather on bf16 Y rows; fp32 output.
// ---------------------------------------------------------------------------
__global__ __launch_bounds__(256) void node_gather_k(
    const int* __restrict__ off, const int* __restrict__ idx,
    const int* __restrict__ cnt, const uint4* __restrict__ Yb,
    float* __restrict__ Out) {
  const int g = blockIdx.x * blockDim.x + threadIdx.x;
  const int v = g >> 3, q = g & 7;
  if (v >= NUM_NODES) return;
  const int beg = off[NUM_EDGES + v], end = off[NUM_EDGES + v + 1];
  float acc[8];
#pragma unroll
  for (int i = 0; i < 8; ++i) acc[i] = 0.f;
  for (int m = beg; m < end; ++m) {
    const int e = idx[m];
    const uint4 w = Yb[e * 8 + q];
    float lo, hi;
    unpack_acc(w.x, lo, hi); acc[0] += lo; acc[1] += hi;
    unpack_acc(w.y, lo, hi); acc[2] += lo; acc[3] += hi;
    unpack_acc(w.z, lo, hi); acc[4] += lo; acc[5] += hi;
    unpack_acc(w.w, lo, hi); acc[6] += lo; acc[7] += hi;
  }
  const float d = (float)cnt[NUM_EDGES + v];
  const float s = (d > 0.f) ? rsqrtf(d) : 0.f;
  float4* O4 = (float4*)(Out + (size_t)v * D + q * 8);
  O4[0] = make_float4(acc[0] * s, acc[1] * s, acc[2] * s, acc[3] * s);
  O4[1] = make_float4(acc[4] * s, acc[5] * s, acc[6] * s, acc[7] * s);
}

extern "C" void kernel_launch(void* const* d_in, const int* in_sizes, int n_in,
                              void* d_out, int out_size, void* d_ws, size_t ws_size,
                              hipStream_t stream) {
  const float* X = (const float*)d_in[0];
  const int*   V = (const int*)d_in[1];
  const int*   E = (const int*)d_in[2];
  const float* W = (const float*)d_in[4];
  const float* b = (const float*)d_in[5];
  float* Out = (float*)d_out;

  // workspace layout (~41 MB)
  unsigned short* Xpb = (unsigned short*)d_ws;                 // 12.8 MB bf16
  unsigned short* Ybu = Xpb + (size_t)NUM_NODES * D;           // 12.8 MB bf16
  int*      cntb   = (int*)(Ybu + (size_t)NUM_EDGES * D);      // 1564
  int*      bktoff = cntb + NBKT_TOT;                          // 1565
  int*      curb   = bktoff + NBKT_TOT + 1;                    // 1564
  int*      off    = curb + NBKT_TOT;                          // N2+1 (800 KB)
  int*      cnt    = off + N2 + 1;                             // N2   (800 KB)
  unsigned* pair   = (unsigned*)(cnt + N2);                    // 2*NNZ = 12.8 MB
  int*      idx    = (int*)pair;                               // in-place CSR

  hipMemsetAsync(cntb, 0, (size_t)NBKT_TOT * sizeof(int), stream);

  gemm_xw<<<NUM_NODES / GEMM_ROWS, 256, 0, stream>>>(X, W, b, Xpb);
  tile_hist_k<<<NT_H, 256, 0, stream>>>(V, E, cntb);
  scan_bkt_k<<<1, 256, 0, stream>>>(cntb, bktoff, curb);
  bin_tile_k<<<2 * NT_SIDE, 1024, 0, stream>>>(V, E, curb, pair);
  fill_local_k<<<NBKT_TOT, 512, 0, stream>>>(bktoff, pair, off, cnt);
  edge_gather_k<<<NUM_EDGES * 8 / 256, 256, 0, stream>>>(
      off, idx, cnt, (const uint4*)Xpb, (uint4*)Ybu);
  node_gather_k<<<NUM_NODES * 8 / 256, 256, 0, stream>>>(
      off, idx, cnt, (const uint4*)Ybu, Out);
}

// Round 9
// 215.846 us; speedup vs baseline: 10.9490x; 1.1925x over previous
//
#include <hip/hip_runtime.h>
#include <hip/hip_bf16.h>

#define NUM_NODES 100000
#define NUM_EDGES 100000
#define NNZ       1600000
#define D         64

#define N2 (NUM_EDGES + NUM_NODES)          // 200000 concatenated targets

#define BKT     128                          // targets per bucket
#define NBKT_E  ((NUM_EDGES + BKT - 1) / BKT)   // 782
#define NBKT_V  ((NUM_NODES + BKT - 1) / BKT)   // 782
#define NBKT_TOT (NBKT_E + NBKT_V)              // 1564
#define CAP     2816                         // padded words per bucket segment
                                             // (mean 2048, sigma~45 -> +17 sigma)

#define TILE 8192                            // entries per bin tile
#define NT_SIDE ((NNZ + TILE - 1) / TILE)    // 196 tiles per side

// ---- bf16 helpers (RNE pack, shift unpack) --------------------------------
__device__ inline unsigned pack_bf16x2(float a, float b) {
  unsigned ua = __float_as_uint(a), ub = __float_as_uint(b);
  ua = (ua + 0x7fffu + ((ua >> 16) & 1u)) >> 16;
  ub = (ub + 0x7fffu + ((ub >> 16) & 1u)) >> 16;
  return ua | (ub << 16);
}
__device__ inline void unpack_acc(unsigned u, float& lo, float& hi) {
  lo = __uint_as_float(u << 16);
  hi = __uint_as_float(u & 0xffff0000u);
}

// ---------------------------------------------------------------------------
// Kernel 1: Xp = bf16(X @ W^T + b)
// ---------------------------------------------------------------------------
#define GEMM_ROWS 32
__global__ __launch_bounds__(256) void gemm_xw(
    const float* __restrict__ X, const float* __restrict__ W,
    const float* __restrict__ b, unsigned short* __restrict__ Xpb) {
  __shared__ float Wl[D][D + 1];
  __shared__ float Xl[GEMM_ROWS][D];
  const int t = threadIdx.x;

  for (int j = t; j < D * D; j += 256) Wl[j >> 6][j & 63] = W[j];
  const int row0 = blockIdx.x * GEMM_ROWS;
  const float4* X4 = (const float4*)(X + (size_t)row0 * D);
  float4* Xl4 = (float4*)&Xl[0][0];
  for (int j = t; j < GEMM_ROWS * (D / 4); j += 256) Xl4[j] = X4[j];
  __syncthreads();

  const int c = t & 63;
  const int rq = t >> 6;
  float acc[8];
#pragma unroll
  for (int i = 0; i < 8; ++i) acc[i] = 0.f;
#pragma unroll
  for (int k = 0; k < D; ++k) {
    const float w = Wl[c][k];
#pragma unroll
    for (int i = 0; i < 8; ++i) acc[i] = fmaf(Xl[rq + i * 4][k], w, acc[i]);
  }
  const float bias = b[c];
#pragma unroll
  for (int i = 0; i < 8; ++i) {
    const int r = row0 + rq + i * 4;
    const float v = acc[i] + bias;
    unsigned u = __float_as_uint(v);
    u = (u + 0x7fffu + ((u >> 16) & 1u)) >> 16;
    Xpb[(size_t)r * D + c] = (unsigned short)u;
  }
}

// ---------------------------------------------------------------------------
// Kernel 2: init bucket cursors to padded segment bases (b*CAP).
// (scan-less layout: no global histogram/scan needed at all)
// ---------------------------------------------------------------------------
__global__ __launch_bounds__(256) void curb_init_k(int* __restrict__ curb) {
  const int b = blockIdx.x * blockDim.x + threadIdx.x;
  if (b < NBKT_TOT) curb[b] = b * CAP;
}

// ---------------------------------------------------------------------------
// Kernel 3: tile-local counting sort + bulk-reserved contiguous write-out.
// (round-8 proven: 1024 threads, binary-search write-out)
// ---------------------------------------------------------------------------
__global__ __launch_bounds__(1024, 4) void bin_tile_k(
    const int* __restrict__ V, const int* __restrict__ E,
    int* __restrict__ curb, unsigned* __restrict__ pair) {
  __shared__ unsigned stage[TILE];            // 32 KB
  __shared__ int hist[NBKT_E];                // counts -> exclusive offsets
  __shared__ int gbase[NBKT_E];
  __shared__ int lcur[NBKT_E];
  __shared__ int part[1024];

  const int t = threadIdx.x;
  const int side = (blockIdx.x >= NT_SIDE) ? 1 : 0;
  const int bt = blockIdx.x - side * NT_SIDE;
  const int j0 = bt * TILE;
  const int n = (NNZ - j0 < TILE) ? (NNZ - j0) : TILE;
  const int cbase = side ? NBKT_E : 0;

  for (int i = t; i < NBKT_E; i += 1024) hist[i] = 0;
  __syncthreads();

  // phase 1: tile histogram
#pragma unroll
  for (int k = 0; k < TILE / 1024; ++k) {
    const int j = j0 + t + k * 1024;
    if (j - j0 < n) {
      const int key = side ? V[j] : E[j];
      atomicAdd(&hist[key >> 7], 1);
    }
  }
  __syncthreads();

  // phase 2: scan (1 bucket/thread) + one global reservation per bucket
  const int cb = (t < NBKT_E) ? hist[t] : 0;
  part[t] = cb;
  __syncthreads();
  for (int st = 1; st < 1024; st <<= 1) {
    const int x = part[t];
    const int add = (t >= st) ? part[t - st] : 0;
    __syncthreads();
    part[t] = x + add;
    __syncthreads();
  }
  if (t < NBKT_E) {
    const int o = part[t] - cb;   // exclusive local offset
    hist[t] = o;
    lcur[t] = o;
    gbase[t] = cb ? atomicAdd(&curb[cbase + t], cb) : 0;
  }
  __syncthreads();

  // phase 3: local bucket-sort into stage
#pragma unroll
  for (int k = 0; k < TILE / 1024; ++k) {
    const int j = j0 + t + k * 1024;
    if (j - j0 < n) {
      const int v = V[j], e = E[j];
      const int key = side ? v : e;
      const int src = side ? e : v;
      const int b = key >> 7;
      const unsigned w = ((unsigned)src << 7) | (unsigned)(key & 127);
      const int pos = atomicAdd(&lcur[b], 1);
      stage[pos] = w;
    }
  }
  __syncthreads();

  // phase 4: dense write-out; bucket via binary search over hist offsets
  for (int sI = t; sI < n; sI += 1024) {
    int lo = 0, hi = NBKT_E - 1;
    while (lo < hi) {
      const int mid = (lo + hi + 1) >> 1;
      if (hist[mid] <= sI) lo = mid; else hi = mid - 1;
    }
    pair[gbase[lo] + (sI - hist[lo])] = stage[sI];
  }
}

// ---------------------------------------------------------------------------
// Kernel 4: per-bucket CSR placement IN PLACE + per-target off/cnt emission.
// Segment length derived from the post-bin cursor (scan-less layout).
// ---------------------------------------------------------------------------
__global__ __launch_bounds__(512) void fill_local_k(
    const int* __restrict__ curb, unsigned* __restrict__ pair,
    int* __restrict__ off, int* __restrict__ cnt) {
  __shared__ unsigned seg[CAP];
  __shared__ int rcnt[BKT];
  __shared__ int sc[BKT];
  __shared__ int lcur[BKT];
  const int b = blockIdx.x, t = threadIdx.x;
  int ct0, nrows;
  if (b < NBKT_E) {
    const int e0 = b * BKT;
    ct0 = e0;
    nrows = (NUM_EDGES - e0 < BKT) ? (NUM_EDGES - e0) : BKT;
  } else {
    const int v0 = (b - NBKT_E) * BKT;
    ct0 = NUM_EDGES + v0;
    nrows = (NUM_NODES - v0 < BKT) ? (NUM_NODES - v0) : BKT;
  }
  const int beg = b * CAP;
  int n = curb[b] - beg;
  if (n > CAP) n = CAP;   // insurance (deterministic inputs keep n < CAP)

  if (t < BKT) rcnt[t] = 0;
  __syncthreads();

  for (int j = t; j < n; j += 512) {
    const unsigned w = pair[beg + j];
    seg[j] = w;
    atomicAdd(&rcnt[w & 127u], 1);
  }
  __syncthreads();

  if (t < BKT) sc[t] = rcnt[t];
  __syncthreads();
  for (int st = 1; st < BKT; st <<= 1) {
    int v = 0;
    if (t < BKT) v = (t >= st) ? sc[t - st] + sc[t] : sc[t];
    __syncthreads();
    if (t < BKT) sc[t] = v;
    __syncthreads();
  }
  if (t < BKT) {
    const int o = beg + sc[t] - rcnt[t];   // exclusive, within padded segment
    lcur[t] = o;
    if (t < nrows) {
      off[ct0 + t] = o;
      cnt[ct0 + t] = rcnt[t];
    }
  }
  __syncthreads();

  int* idx = (int*)pair;
  for (int j = t; j < n; j += 512) {
    const unsigned w = seg[j];
    const int pos = atomicAdd(&lcur[w & 127u], 1);
    idx[pos] = (int)(w >> 7);
  }
}

// ---------------------------------------------------------------------------
// Kernel 5: per-edge gather, bf16 rows, 8 lanes/edge, UNROLL-4 for MLP.
// end = off[e] + cnt[e] (padded layout).  Fused De/cnt normalization.
// ---------------------------------------------------------------------------
__global__ __launch_bounds__(256) void edge_gather_k(
    const int* __restrict__ off, const int* __restrict__ idx,
    const int* __restrict__ cnt, const uint4* __restrict__ Xpb,
    uint4* __restrict__ Yb) {
  const int g = blockIdx.x * blockDim.x + threadIdx.x;
  const int e = g >> 3, q = g & 7;
  if (e >= NUM_EDGES) return;
  const int beg = off[e];
  const int ne = cnt[e];
  const int end = beg + ne;
  float acc[8];
#pragma unroll
  for (int i = 0; i < 8; ++i) acc[i] = 0.f;
  float dsum = 0.f;
  int m = beg;
  for (; m + 3 < end; m += 4) {
    const int v0 = idx[m], v1 = idx[m + 1], v2 = idx[m + 2], v3 = idx[m + 3];
    const uint4 w0 = Xpb[v0 * 8 + q];
    const uint4 w1 = Xpb[v1 * 8 + q];
    const uint4 w2 = Xpb[v2 * 8 + q];
    const uint4 w3 = Xpb[v3 * 8 + q];
    const float d0 = (float)cnt[NUM_EDGES + v0];
    const float d1 = (float)cnt[NUM_EDGES + v1];
    const float d2 = (float)cnt[NUM_EDGES + v2];
    const float d3 = (float)cnt[NUM_EDGES + v3];
    dsum += (d0 + d1) + (d2 + d3);
    float lo, hi;
    unpack_acc(w0.x, lo, hi); acc[0] += lo; acc[1] += hi;
    unpack_acc(w0.y, lo, hi); acc[2] += lo; acc[3] += hi;
    unpack_acc(w0.z, lo, hi); acc[4] += lo; acc[5] += hi;
    unpack_acc(w0.w, lo, hi); acc[6] += lo; acc[7] += hi;
    unpack_acc(w1.x, lo, hi); acc[0] += lo; acc[1] += hi;
    unpack_acc(w1.y, lo, hi); acc[2] += lo; acc[3] += hi;
    unpack_acc(w1.z, lo, hi); acc[4] += lo; acc[5] += hi;
    unpack_acc(w1.w, lo, hi); acc[6] += lo; acc[7] += hi;
    unpack_acc(w2.x, lo, hi); acc[0] += lo; acc[1] += hi;
    unpack_acc(w2.y, lo, hi); acc[2] += lo; acc[3] += hi;
    unpack_acc(w2.z, lo, hi); acc[4] += lo; acc[5] += hi;
    unpack_acc(w2.w, lo, hi); acc[6] += lo; acc[7] += hi;
    unpack_acc(w3.x, lo, hi); acc[0] += lo; acc[1] += hi;
    unpack_acc(w3.y, lo, hi); acc[2] += lo; acc[3] += hi;
    unpack_acc(w3.z, lo, hi); acc[4] += lo; acc[5] += hi;
    unpack_acc(w3.w, lo, hi); acc[6] += lo; acc[7] += hi;
  }
  for (; m < end; ++m) {
    const int v = idx[m];
    const uint4 w = Xpb[v * 8 + q];
    dsum += (float)cnt[NUM_EDGES + v];
    float lo, hi;
    unpack_acc(w.x, lo, hi); acc[0] += lo; acc[1] += hi;
    unpack_acc(w.y, lo, hi); acc[2] += lo; acc[3] += hi;
    unpack_acc(w.z, lo, hi); acc[4] += lo; acc[5] += hi;
    unpack_acc(w.w, lo, hi); acc[6] += lo; acc[7] += hi;
  }
  const float ce = (float)ne;
  const float De = dsum / (ce + 1.f);
  const float inv = (De > 0.f) ? rsqrtf(fmaxf(De, 1e-30f)) : 1.f;
  const float s = inv / fmaxf(ce, 1.f);
  uint4 o;
  o.x = pack_bf16x2(acc[0] * s, acc[1] * s);
  o.y = pack_bf16x2(acc[2] * s, acc[3] * s);
  o.z = pack_bf16x2(acc[4] * s, acc[5] * s);
  o.w = pack_bf16x2(acc[6] * s, acc[7] * s);
  Yb[e * 8 + q] = o;
}

// ---------------------------------------------------------------------------
// Kernel 6: per-node gather, bf16 Y rows, UNROLL-4; fp32 output.
// ---------------------------------------------------------------------------
__global__ __launch_bounds__(256) void node_gather_k(
    const int* __restrict__ off, const int* __restrict__ idx,
    const int* __restrict__ cnt, const uint4* __restrict__ Yb,
    float* __restrict__ Out) {
  const int g = blockIdx.x * blockDim.x + threadIdx.x;
  const int v = g >> 3, q = g & 7;
  if (v >= NUM_NODES) return;
  const int beg = off[NUM_EDGES + v];
  const int dv = cnt[NUM_EDGES + v];
  const int end = beg + dv;
  float acc[8];
#pragma unroll
  for (int i = 0; i < 8; ++i) acc[i] = 0.f;
  int m = beg;
  for (; m + 3 < end; m += 4) {
    const int e0 = idx[m], e1 = idx[m + 1], e2 = idx[m + 2], e3 = idx[m + 3];
    const uint4 w0 = Yb[e0 * 8 + q];
    const uint4 w1 = Yb[e1 * 8 + q];
    const uint4 w2 = Yb[e2 * 8 + q];
    const uint4 w3 = Yb[e3 * 8 + q];
    float lo, hi;
    unpack_acc(w0.x, lo, hi); acc[0] += lo; acc[1] += hi;
    unpack_acc(w0.y, lo, hi); acc[2] += lo; acc[3] += hi;
    unpack_acc(w0.z, lo, hi); acc[4] += lo; acc[5] += hi;
    unpack_acc(w0.w, lo, hi); acc[6] += lo; acc[7] += hi;
    unpack_acc(w1.x, lo, hi); acc[0] += lo; acc[1] += hi;
    unpack_acc(w1.y, lo, hi); acc[2] += lo; acc[3] += hi;
    unpack_acc(w1.z, lo, hi); acc[4] += lo; acc[5] += hi;
    unpack_acc(w1.w, lo, hi); acc[6] += lo; acc[7] += hi;
    unpack_acc(w2.x, lo, hi); acc[0] += lo; acc[1] += hi;
    unpack_acc(w2.y, lo, hi); acc[2] += lo; acc[3] += hi;
    unpack_acc(w2.z, lo, hi); acc[4] += lo; acc[5] += hi;
    unpack_acc(w2.w, lo, hi); acc[6] += lo; acc[7] += hi;
    unpack_acc(w3.x, lo, hi); acc[0] += lo; acc[1] += hi;
    unpack_acc(w3.y, lo, hi); acc[2] += lo; acc[3] += hi;
    unpack_acc(w3.z, lo, hi); acc[4] += lo; acc[5] += hi;
    unpack_acc(w3.w, lo, hi); acc[6] += lo; acc[7] += hi;
  }
  for (; m < end; ++m) {
    const uint4 w = Yb[idx[m] * 8 + q];
    float lo, hi;
    unpack_acc(w.x, lo, hi); acc[0] += lo; acc[1] += hi;
    unpack_acc(w.y, lo, hi); acc[2] += lo; acc[3] += hi;
    unpack_acc(w.z, lo, hi); acc[4] += lo; acc[5] += hi;
    unpack_acc(w.w, lo, hi); acc[6] += lo; acc[7] += hi;
  }
  const float d = (float)dv;
  const float s = (d > 0.f) ? rsqrtf(d) : 0.f;
  float4* O4 = (float4*)(Out + (size_t)v * D + q * 8);
  O4[0] = make_float4(acc[0] * s, acc[1] * s, acc[2] * s, acc[3] * s);
  O4[1] = make_float4(acc[4] * s, acc[5] * s, acc[6] * s, acc[7] * s);
}

extern "C" void kernel_launch(void* const* d_in, const int* in_sizes, int n_in,
                              void* d_out, int out_size, void* d_ws, size_t ws_size,
                              hipStream_t stream) {
  const float* X = (const float*)d_in[0];
  const int*   V = (const int*)d_in[1];
  const int*   E = (const int*)d_in[2];
  const float* W = (const float*)d_in[4];
  const float* b = (const float*)d_in[5];
  float* Out = (float*)d_out;

  // workspace layout (~45 MB)
  unsigned short* Xpb = (unsigned short*)d_ws;                 // 12.8 MB bf16
  unsigned short* Ybu = Xpb + (size_t)NUM_NODES * D;           // 12.8 MB bf16
  int*      curb   = (int*)(Ybu + (size_t)NUM_EDGES * D);      // 1564
  int*      off    = curb + NBKT_TOT;                          // N2 (800 KB)
  int*      cnt    = off + N2;                                 // N2 (800 KB)
  unsigned* pair   = (unsigned*)(cnt + N2);                    // NBKT_TOT*CAP = 17.6 MB
  int*      idx    = (int*)pair;                               // in-place CSR

  gemm_xw<<<NUM_NODES / GEMM_ROWS, 256, 0, stream>>>(X, W, b, Xpb);
  curb_init_k<<<(NBKT_TOT + 255) / 256, 256, 0, stream>>>(curb);
  bin_tile_k<<<2 * NT_SIDE, 1024, 0, stream>>>(V, E, curb, pair);
  fill_local_k<<<NBKT_TOT, 512, 0, stream>>>(curb, pair, off, cnt);
  edge_gather_k<<<NUM_EDGES * 8 / 256, 256, 0, stream>>>(
      off, idx, cnt, (const uint4*)Xpb, (uint4*)Ybu);
  node_gather_k<<<NUM_NODES * 8 / 256, 256, 0, stream>>>(
      off, idx, cnt, (const uint4*)Ybu, Out);
}

// Round 10
// 207.592 us; speedup vs baseline: 11.3844x; 1.0398x over previous
//
#include <hip/hip_runtime.h>
#include <hip/hip_bf16.h>

#define NUM_NODES 100000
#define NUM_EDGES 100000
#define NNZ       1600000
#define D         64

#define BKT     128                          // targets per bucket
#define NBKT_E  ((NUM_EDGES + BKT - 1) / BKT)   // 782
#define NBKT_V  ((NUM_NODES + BKT - 1) / BKT)   // 782
#define NBKT_TOT (NBKT_E + NBKT_V)              // 1564
#define CAP     2816                         // padded words per bucket segment

#define TILE 8192                            // entries per bin tile
#define NT_SIDE ((NNZ + TILE - 1) / TILE)    // 196 tiles per side

// ---- bf16 helpers (RNE pack, shift unpack) --------------------------------
__device__ inline unsigned pack_bf16x2(float a, float b) {
  unsigned ua = __float_as_uint(a), ub = __float_as_uint(b);
  ua = (ua + 0x7fffu + ((ua >> 16) & 1u)) >> 16;
  ub = (ub + 0x7fffu + ((ub >> 16) & 1u)) >> 16;
  return ua | (ub << 16);
}
__device__ inline void unpack_acc(unsigned u, float& lo, float& hi) {
  lo = __uint_as_float(u << 16);
  hi = __uint_as_float(u & 0xffff0000u);
}

// ---------------------------------------------------------------------------
// Kernel 1: Xp = bf16(X @ W^T + b)
// ---------------------------------------------------------------------------
#define GEMM_ROWS 32
__global__ __launch_bounds__(256) void gemm_xw(
    const float* __restrict__ X, const float* __restrict__ W,
    const float* __restrict__ b, unsigned short* __restrict__ Xpb) {
  __shared__ float Wl[D][D + 1];
  __shared__ float Xl[GEMM_ROWS][D];
  const int t = threadIdx.x;

  for (int j = t; j < D * D; j += 256) Wl[j >> 6][j & 63] = W[j];
  const int row0 = blockIdx.x * GEMM_ROWS;
  const float4* X4 = (const float4*)(X + (size_t)row0 * D);
  float4* Xl4 = (float4*)&Xl[0][0];
  for (int j = t; j < GEMM_ROWS * (D / 4); j += 256) Xl4[j] = X4[j];
  __syncthreads();

  const int c = t & 63;
  const int rq = t >> 6;
  float acc[8];
#pragma unroll
  for (int i = 0; i < 8; ++i) acc[i] = 0.f;
#pragma unroll
  for (int k = 0; k < D; ++k) {
    const float w = Wl[c][k];
#pragma unroll
    for (int i = 0; i < 8; ++i) acc[i] = fmaf(Xl[rq + i * 4][k], w, acc[i]);
  }
  const float bias = b[c];
#pragma unroll
  for (int i = 0; i < 8; ++i) {
    const int r = row0 + rq + i * 4;
    const float v = acc[i] + bias;
    unsigned u = __float_as_uint(v);
    u = (u + 0x7fffu + ((u >> 16) & 1u)) >> 16;
    Xpb[(size_t)r * D + c] = (unsigned short)u;
  }
}

// ---------------------------------------------------------------------------
// Kernel 2: init bucket cursors to padded segment bases (b*CAP).
// ---------------------------------------------------------------------------
__global__ __launch_bounds__(256) void curb_init_k(int* __restrict__ curb) {
  const int b = blockIdx.x * blockDim.x + threadIdx.x;
  if (b < NBKT_TOT) curb[b] = b * CAP;
}

// ---------------------------------------------------------------------------
// Kernel 3: tile-local counting sort + bulk-reserved contiguous write-out.
// (round-8 proven: 1024 threads, binary-search write-out)
// ---------------------------------------------------------------------------
__global__ __launch_bounds__(1024, 4) void bin_tile_k(
    const int* __restrict__ V, const int* __restrict__ E,
    int* __restrict__ curb, unsigned* __restrict__ pair) {
  __shared__ unsigned stage[TILE];            // 32 KB
  __shared__ int hist[NBKT_E];                // counts -> exclusive offsets
  __shared__ int gbase[NBKT_E];
  __shared__ int lcur[NBKT_E];
  __shared__ int part[1024];

  const int t = threadIdx.x;
  const int side = (blockIdx.x >= NT_SIDE) ? 1 : 0;
  const int bt = blockIdx.x - side * NT_SIDE;
  const int j0 = bt * TILE;
  const int n = (NNZ - j0 < TILE) ? (NNZ - j0) : TILE;
  const int cbase = side ? NBKT_E : 0;

  for (int i = t; i < NBKT_E; i += 1024) hist[i] = 0;
  __syncthreads();

  // phase 1: tile histogram
#pragma unroll
  for (int k = 0; k < TILE / 1024; ++k) {
    const int j = j0 + t + k * 1024;
    if (j - j0 < n) {
      const int key = side ? V[j] : E[j];
      atomicAdd(&hist[key >> 7], 1);
    }
  }
  __syncthreads();

  // phase 2: scan + one global reservation per bucket
  const int cb = (t < NBKT_E) ? hist[t] : 0;
  part[t] = cb;
  __syncthreads();
  for (int st = 1; st < 1024; st <<= 1) {
    const int x = part[t];
    const int add = (t >= st) ? part[t - st] : 0;
    __syncthreads();
    part[t] = x + add;
    __syncthreads();
  }
  if (t < NBKT_E) {
    const int o = part[t] - cb;   // exclusive local offset
    hist[t] = o;
    lcur[t] = o;
    gbase[t] = cb ? atomicAdd(&curb[cbase + t], cb) : 0;
  }
  __syncthreads();

  // phase 3: local bucket-sort into stage
#pragma unroll
  for (int k = 0; k < TILE / 1024; ++k) {
    const int j = j0 + t + k * 1024;
    if (j - j0 < n) {
      const int v = V[j], e = E[j];
      const int key = side ? v : e;
      const int src = side ? e : v;
      const int b = key >> 7;
      const unsigned w = ((unsigned)src << 7) | (unsigned)(key & 127);
      const int pos = atomicAdd(&lcur[b], 1);
      stage[pos] = w;
    }
  }
  __syncthreads();

  // phase 4: dense write-out; bucket via binary search over hist offsets
  for (int sI = t; sI < n; sI += 1024) {
    int lo = 0, hi = NBKT_E - 1;
    while (lo < hi) {
      const int mid = (lo + hi + 1) >> 1;
      if (hist[mid] <= sI) lo = mid; else hi = mid - 1;
    }
    pair[gbase[lo] + (sI - hist[lo])] = stage[sI];
  }
}

// ---------------------------------------------------------------------------
// Kernel 4: node degrees from node-side segments (needed by edge gather).
// One block per node bucket; LDS histogram; 512 B dense write per block.
// ---------------------------------------------------------------------------
__global__ __launch_bounds__(256) void deg_node_k(
    const int* __restrict__ curb, const unsigned* __restrict__ pair,
    int* __restrict__ cnt_v) {
  __shared__ int rcnt[BKT];
  const int b = blockIdx.x, t = threadIdx.x;
  const int base = (NBKT_E + b) * CAP;
  int n = curb[NBKT_E + b] - base;
  if (n > CAP) n = CAP;
  if (t < BKT) rcnt[t] = 0;
  __syncthreads();
  for (int j = t; j < n; j += 256) {
    atomicAdd(&rcnt[pair[base + j] & 127u], 1);
  }
  __syncthreads();
  const int v = b * BKT + t;
  if (t < BKT && v < NUM_NODES) cnt_v[v] = rcnt[t];
}

// ---------------------------------------------------------------------------
// Kernel 5: FUSED edge pass. One block = one edge bucket (128 edges).
// Stage segment -> LDS row-sort -> gather Xp rows with member ids from LDS.
// CSR idx/off never touch global. Fused De/cnt normalization; bf16 Y write.
// ---------------------------------------------------------------------------
__global__ __launch_bounds__(512) void edge_fused_k(
    const int* __restrict__ curb, const unsigned* __restrict__ pair,
    const int* __restrict__ cnt_v, const uint4* __restrict__ Xpb,
    uint4* __restrict__ Yb) {
  __shared__ unsigned seg[CAP];
  __shared__ int sorted_[CAP];
  __shared__ int rcnt[BKT];
  __shared__ int sc[BKT];
  __shared__ int lcur[BKT];
  const int b = blockIdx.x, t = threadIdx.x;
  const int base = b * CAP;
  int n = curb[b] - base;
  if (n > CAP) n = CAP;
  const int e0 = b * BKT;
  const int nrows = (NUM_EDGES - e0 < BKT) ? (NUM_EDGES - e0) : BKT;

  if (t < BKT) rcnt[t] = 0;
  __syncthreads();

  for (int j = t; j < n; j += 512) {
    const unsigned w = pair[base + j];
    seg[j] = w;
    atomicAdd(&rcnt[w & 127u], 1);
  }
  __syncthreads();

  // exclusive scan of 128 row counts
  if (t < BKT) sc[t] = rcnt[t];
  __syncthreads();
  for (int st = 1; st < BKT; st <<= 1) {
    int v = 0;
    if (t < BKT) v = (t >= st) ? sc[t - st] + sc[t] : sc[t];
    __syncthreads();
    if (t < BKT) sc[t] = v;
    __syncthreads();
  }
  if (t < BKT) lcur[t] = sc[t] - rcnt[t];
  __syncthreads();

  // row-sort member ids into LDS
  for (int j = t; j < n; j += 512) {
    const unsigned w = seg[j];
    const int pos = atomicAdd(&lcur[w & 127u], 1);
    sorted_[pos] = (int)(w >> 7);
  }
  __syncthreads();

  // gather: 8 lanes per row, 64 rows per pass, 2 passes
  const int q = t & 7;
#pragma unroll
  for (int rr = 0; rr < 2; ++rr) {
    const int row = (t >> 3) + rr * 64;
    const int ne = rcnt[row];
    const int mb = sc[row] - ne;
    const int me = sc[row];
    float acc[8];
#pragma unroll
    for (int i = 0; i < 8; ++i) acc[i] = 0.f;
    float dsum = 0.f;
    int m = mb;
    for (; m + 3 < me; m += 4) {
      const int v0 = sorted_[m], v1 = sorted_[m + 1];
      const int v2 = sorted_[m + 2], v3 = sorted_[m + 3];
      const uint4 w0 = Xpb[v0 * 8 + q];
      const uint4 w1 = Xpb[v1 * 8 + q];
      const uint4 w2 = Xpb[v2 * 8 + q];
      const uint4 w3 = Xpb[v3 * 8 + q];
      const float d0 = (float)cnt_v[v0];
      const float d1 = (float)cnt_v[v1];
      const float d2 = (float)cnt_v[v2];
      const float d3 = (float)cnt_v[v3];
      dsum += (d0 + d1) + (d2 + d3);
      float lo, hi;
      unpack_acc(w0.x, lo, hi); acc[0] += lo; acc[1] += hi;
      unpack_acc(w0.y, lo, hi); acc[2] += lo; acc[3] += hi;
      unpack_acc(w0.z, lo, hi); acc[4] += lo; acc[5] += hi;
      unpack_acc(w0.w, lo, hi); acc[6] += lo; acc[7] += hi;
      unpack_acc(w1.x, lo, hi); acc[0] += lo; acc[1] += hi;
      unpack_acc(w1.y, lo, hi); acc[2] += lo; acc[3] += hi;
      unpack_acc(w1.z, lo, hi); acc[4] += lo; acc[5] += hi;
      unpack_acc(w1.w, lo, hi); acc[6] += lo; acc[7] += hi;
      unpack_acc(w2.x, lo, hi); acc[0] += lo; acc[1] += hi;
      unpack_acc(w2.y, lo, hi); acc[2] += lo; acc[3] += hi;
      unpack_acc(w2.z, lo, hi); acc[4] += lo; acc[5] += hi;
      unpack_acc(w2.w, lo, hi); acc[6] += lo; acc[7] += hi;
      unpack_acc(w3.x, lo, hi); acc[0] += lo; acc[1] += hi;
      unpack_acc(w3.y, lo, hi); acc[2] += lo; acc[3] += hi;
      unpack_acc(w3.z, lo, hi); acc[4] += lo; acc[5] += hi;
      unpack_acc(w3.w, lo, hi); acc[6] += lo; acc[7] += hi;
    }
    for (; m < me; ++m) {
      const int v = sorted_[m];
      const uint4 w = Xpb[v * 8 + q];
      dsum += (float)cnt_v[v];
      float lo, hi;
      unpack_acc(w.x, lo, hi); acc[0] += lo; acc[1] += hi;
      unpack_acc(w.y, lo, hi); acc[2] += lo; acc[3] += hi;
      unpack_acc(w.z, lo, hi); acc[4] += lo; acc[5] += hi;
      unpack_acc(w.w, lo, hi); acc[6] += lo; acc[7] += hi;
    }
    const float ce = (float)ne;
    const float De = dsum / (ce + 1.f);
    const float inv = (De > 0.f) ? rsqrtf(fmaxf(De, 1e-30f)) : 1.f;
    const float s = inv / fmaxf(ce, 1.f);
    if (row < nrows) {
      uint4 o;
      o.x = pack_bf16x2(acc[0] * s, acc[1] * s);
      o.y = pack_bf16x2(acc[2] * s, acc[3] * s);
      o.z = pack_bf16x2(acc[4] * s, acc[5] * s);
      o.w = pack_bf16x2(acc[6] * s, acc[7] * s);
      Yb[(e0 + row) * 8 + q] = o;
    }
  }
}

// ---------------------------------------------------------------------------
// Kernel 6: FUSED node pass. One block = one node bucket (128 nodes).
// Stage -> LDS row-sort -> gather Y rows -> Out = rsqrt(D_v) * sum.
// ---------------------------------------------------------------------------
__global__ __launch_bounds__(512) void node_fused_k(
    const int* __restrict__ curb, const unsigned* __restrict__ pair,
    const uint4* __restrict__ Yb, float* __restrict__ Out) {
  __shared__ unsigned seg[CAP];
  __shared__ int sorted_[CAP];
  __shared__ int rcnt[BKT];
  __shared__ int sc[BKT];
  __shared__ int lcur[BKT];
  const int b = blockIdx.x, t = threadIdx.x;
  const int base = (NBKT_E + b) * CAP;
  int n = curb[NBKT_E + b] - base;
  if (n > CAP) n = CAP;
  const int v0r = b * BKT;
  const int nrows = (NUM_NODES - v0r < BKT) ? (NUM_NODES - v0r) : BKT;

  if (t < BKT) rcnt[t] = 0;
  __syncthreads();

  for (int j = t; j < n; j += 512) {
    const unsigned w = pair[base + j];
    seg[j] = w;
    atomicAdd(&rcnt[w & 127u], 1);
  }
  __syncthreads();

  if (t < BKT) sc[t] = rcnt[t];
  __syncthreads();
  for (int st = 1; st < BKT; st <<= 1) {
    int v = 0;
    if (t < BKT) v = (t >= st) ? sc[t - st] + sc[t] : sc[t];
    __syncthreads();
    if (t < BKT) sc[t] = v;
    __syncthreads();
  }
  if (t < BKT) lcur[t] = sc[t] - rcnt[t];
  __syncthreads();

  for (int j = t; j < n; j += 512) {
    const unsigned w = seg[j];
    const int pos = atomicAdd(&lcur[w & 127u], 1);
    sorted_[pos] = (int)(w >> 7);
  }
  __syncthreads();

  const int q = t & 7;
#pragma unroll
  for (int rr = 0; rr < 2; ++rr) {
    const int row = (t >> 3) + rr * 64;
    const int dv = rcnt[row];
    const int mb = sc[row] - dv;
    const int me = sc[row];
    float acc[8];
#pragma unroll
    for (int i = 0; i < 8; ++i) acc[i] = 0.f;
    int m = mb;
    for (; m + 3 < me; m += 4) {
      const int e0 = sorted_[m], e1 = sorted_[m + 1];
      const int e2 = sorted_[m + 2], e3 = sorted_[m + 3];
      const uint4 w0 = Yb[e0 * 8 + q];
      const uint4 w1 = Yb[e1 * 8 + q];
      const uint4 w2 = Yb[e2 * 8 + q];
      const uint4 w3 = Yb[e3 * 8 + q];
      float lo, hi;
      unpack_acc(w0.x, lo, hi); acc[0] += lo; acc[1] += hi;
      unpack_acc(w0.y, lo, hi); acc[2] += lo; acc[3] += hi;
      unpack_acc(w0.z, lo, hi); acc[4] += lo; acc[5] += hi;
      unpack_acc(w0.w, lo, hi); acc[6] += lo; acc[7] += hi;
      unpack_acc(w1.x, lo, hi); acc[0] += lo; acc[1] += hi;
      unpack_acc(w1.y, lo, hi); acc[2] += lo; acc[3] += hi;
      unpack_acc(w1.z, lo, hi); acc[4] += lo; acc[5] += hi;
      unpack_acc(w1.w, lo, hi); acc[6] += lo; acc[7] += hi;
      unpack_acc(w2.x, lo, hi); acc[0] += lo; acc[1] += hi;
      unpack_acc(w2.y, lo, hi); acc[2] += lo; acc[3] += hi;
      unpack_acc(w2.z, lo, hi); acc[4] += lo; acc[5] += hi;
      unpack_acc(w2.w, lo, hi); acc[6] += lo; acc[7] += hi;
      unpack_acc(w3.x, lo, hi); acc[0] += lo; acc[1] += hi;
      unpack_acc(w3.y, lo, hi); acc[2] += lo; acc[3] += hi;
      unpack_acc(w3.z, lo, hi); acc[4] += lo; acc[5] += hi;
      unpack_acc(w3.w, lo, hi); acc[6] += lo; acc[7] += hi;
    }
    for (; m < me; ++m) {
      const uint4 w = Yb[sorted_[m] * 8 + q];
      float lo, hi;
      unpack_acc(w.x, lo, hi); acc[0] += lo; acc[1] += hi;
      unpack_acc(w.y, lo, hi); acc[2] += lo; acc[3] += hi;
      unpack_acc(w.z, lo, hi); acc[4] += lo; acc[5] += hi;
      unpack_acc(w.w, lo, hi); acc[6] += lo; acc[7] += hi;
    }
    const float d = (float)dv;
    const float s = (d > 0.f) ? rsqrtf(d) : 0.f;
    if (row < nrows) {
      float4* O4 = (float4*)(Out + (size_t)(v0r + row) * D + q * 8);
      O4[0] = make_float4(acc[0] * s, acc[1] * s, acc[2] * s, acc[3] * s);
      O4[1] = make_float4(acc[4] * s, acc[5] * s, acc[6] * s, acc[7] * s);
    }
  }
}

extern "C" void kernel_launch(void* const* d_in, const int* in_sizes, int n_in,
                              void* d_out, int out_size, void* d_ws, size_t ws_size,
                              hipStream_t stream) {
  const float* X = (const float*)d_in[0];
  const int*   V = (const int*)d_in[1];
  const int*   E = (const int*)d_in[2];
  const float* W = (const float*)d_in[4];
  const float* b = (const float*)d_in[5];
  float* Out = (float*)d_out;

  // workspace layout (~44 MB)
  unsigned short* Xpb = (unsigned short*)d_ws;                 // 12.8 MB bf16
  unsigned short* Ybu = Xpb + (size_t)NUM_NODES * D;           // 12.8 MB bf16
  int*      curb   = (int*)(Ybu + (size_t)NUM_EDGES * D);      // 1564
  int*      cnt_v  = curb + NBKT_TOT;                          // 400 KB
  unsigned* pair   = (unsigned*)(cnt_v + NUM_NODES);           // NBKT_TOT*CAP = 17.6 MB

  gemm_xw<<<NUM_NODES / GEMM_ROWS, 256, 0, stream>>>(X, W, b, Xpb);
  curb_init_k<<<(NBKT_TOT + 255) / 256, 256, 0, stream>>>(curb);
  bin_tile_k<<<2 * NT_SIDE, 1024, 0, stream>>>(V, E, curb, pair);
  deg_node_k<<<NBKT_V, 256, 0, stream>>>(curb, pair, cnt_v);
  edge_fused_k<<<NBKT_E, 512, 0, stream>>>(
      curb, pair, cnt_v, (const uint4*)Xpb, (uint4*)Ybu);
  node_fused_k<<<NBKT_V, 512, 0, stream>>>(
      curb, pair, (const uint4*)Ybu, Out);
}